// Round 2
// 1011.083 us; speedup vs baseline: 1.2262x; 1.2262x over previous
//
#include <hip/hip_runtime.h>
#include <hip/hip_bf16.h>

#define N_NODES 50000
#define N_EDGES 800000
#define NBASIS 10
#define NRADIAL 100
#define WNUMEL 192
#define NTILES 12500          // 800000 / 64, exact
#define EDGE_GRID 512
#define HSTRIDE 136           // shorts per h-row (128 + 8 pad; 272 B, 16B-aligned)
#define WSTRIDE 200           // shorts per w-row (192 + 8 pad)
#define WAVE_HW 3200          // shorts per wave region of sHW (16*WSTRIDE; h fits: 16*136=2176)
// s_table: bf16, 384 per node, plane layout:
// [0:64]=s0 | [64:128]=s1x [128:192]=s1y [192:256]=s1z
// [256:288]=s2x [288:320]=s2y [320:352]=s2z | [352:384]=s3

typedef __attribute__((ext_vector_type(8))) short short8;
typedef __attribute__((ext_vector_type(4))) float f32x4;

__device__ __forceinline__ float b2f(__hip_bfloat16 x) { return __bfloat162float(x); }
__device__ __forceinline__ float ldv(const float* p, size_t i) { return p[i]; }
__device__ __forceinline__ float ldv(const __hip_bfloat16* p, size_t i) { return b2f(p[i]); }
__device__ __forceinline__ void stv(float* p, size_t i, float v) { p[i] = v; }
__device__ __forceinline__ void stv(__hip_bfloat16* p, size_t i, float v) { p[i] = __float2bfloat16(v); }

__device__ __forceinline__ bool input_is_f32(const void* node_attr) {
    return ((const unsigned short*)node_attr)[0] == 0;   // bf16(1.0)=0x3F80
}

__device__ __forceinline__ unsigned int pack_bf2(float x, float y) {
    __hip_bfloat162 h;
    h.x = __float2bfloat16(x);
    h.y = __float2bfloat16(y);
    unsigned int u;
    __builtin_memcpy(&u, &h, 4);
    return u;
}

__device__ __forceinline__ void pk_atomic_bf16(__hip_bfloat16* addr, unsigned int data) {
    asm volatile("global_atomic_pk_add_bf16 %0, %1, off"
                 :: "v"((unsigned long long)(uintptr_t)addr), "v"(data)
                 : "memory");
}

// __syncthreads() minus the vmcnt(0) drain: commit this wave's LDS ops, then
// block-barrier. Safe here because no LDS data crosses the barrier carrying a
// VMEM dependency (all VMEM results are register-consumed; compiler inserts
// vmcnt waits for register deps; atomics are fire-and-forget).
__device__ __forceinline__ void sync_lds() {
    asm volatile("s_waitcnt lgkmcnt(0)" ::: "memory");
    __builtin_amdgcn_s_barrier();
}

// ---------------------------------------------------------------------------
// Sort kernels: counting sort of edges by dst.  (R5 known-good versions.)
// ---------------------------------------------------------------------------
__global__ __launch_bounds__(256) void hist_kernel(const int* __restrict__ edge_dst,
                                                   int* __restrict__ counts) {
    int i = blockIdx.x * 256 + threadIdx.x;
    if (i < N_EDGES) atomicAdd(&counts[edge_dst[i]], 1);
}

__global__ __launch_bounds__(1024) void scan_kernel(int* __restrict__ counts) {
    __shared__ int lsum[1024];
    int t = threadIdx.x;
    int lo = t * 49;
    int hi = min(lo + 49, N_NODES);
    int s = 0;
    for (int i = lo; i < hi; ++i) s += counts[i];
    lsum[t] = s;
    __syncthreads();
    for (int off = 1; off < 1024; off <<= 1) {
        int add = (t >= off) ? lsum[t - off] : 0;
        __syncthreads();
        lsum[t] += add;
        __syncthreads();
    }
    int running = lsum[t] - s;   // exclusive prefix
    for (int i = lo; i < hi; ++i) { int c = counts[i]; counts[i] = running; running += c; }
}

__global__ __launch_bounds__(256) void scatter_kernel(const int* __restrict__ edge_dst,
                                                      int* __restrict__ counts,
                                                      int* __restrict__ sorted_idx) {
    int i = blockIdx.x * 256 + threadIdx.x;
    if (i < N_EDGES) {
        int p = atomicAdd(&counts[edge_dst[i]], 1);
        sorted_idx[p] = i;
    }
}

// ---------------------------------------------------------------------------
// Kernel 1: per-node linear l = fctp_scalar(x, W_l1) -> l_table (T, N x 160)
// l_table lives in d_out; overwritten by kernel 3.
// ---------------------------------------------------------------------------
template <class T>
__device__ __forceinline__ void node_linear_body(
    const T* __restrict__ node_input, const T* __restrict__ node_attr,
    const T* __restrict__ W_l1_0, const T* __restrict__ W_l1_1,
    T* __restrict__ l_table)
{
    int wave = (blockIdx.x * 256 + threadIdx.x) >> 6;
    int lane = threadIdx.x & 63;
    if (wave >= N_NODES) return;
    const int n = wave;
    float a = ldv(node_attr, n);
    const T* xrow = node_input + (size_t)n * 160;

    float acc = 0.f;
    for (int u = 0; u < 64; ++u)
        acc += ldv(xrow, u) * ldv(W_l1_0, u * 64 + lane);
    stv(l_table, (size_t)n * 160 + lane, acc * a * 0.125f);

    if (lane < 32) {
        float a0 = 0.f, a1 = 0.f, a2 = 0.f;
        for (int u = 0; u < 32; ++u) {
            float wv = ldv(W_l1_1, u * 32 + lane);
            a0 += ldv(xrow, 64 + u * 3 + 0) * wv;
            a1 += ldv(xrow, 64 + u * 3 + 1) * wv;
            a2 += ldv(xrow, 64 + u * 3 + 2) * wv;
        }
        const float s = a * 0.17677669529663687f;  // 1/sqrt(32)
        stv(l_table, (size_t)n * 160 + 64 + lane * 3 + 0, a0 * s);
        stv(l_table, (size_t)n * 160 + 64 + lane * 3 + 1, a1 * s);
        stv(l_table, (size_t)n * 160 + 64 + lane * 3 + 2, a2 * s);
    }
}

__global__ __launch_bounds__(256) void node_linear_kernel(
    const void* node_input, const void* node_attr,
    const void* W_l1_0, const void* W_l1_1, void* l_table)
{
    if (input_is_f32(node_attr))
        node_linear_body<float>((const float*)node_input, (const float*)node_attr,
                                (const float*)W_l1_0, (const float*)W_l1_1, (float*)l_table);
    else
        node_linear_body<__hip_bfloat16>((const __hip_bfloat16*)node_input,
                                         (const __hip_bfloat16*)node_attr,
                                         (const __hip_bfloat16*)W_l1_0,
                                         (const __hip_bfloat16*)W_l1_1,
                                         (__hip_bfloat16*)l_table);
}

// ---------------------------------------------------------------------------
// flush: pk-bf16 atomic add of 8 accumulator components into s_table[dst].
// ---------------------------------------------------------------------------
__device__ __forceinline__ void flush_acc(
    __hip_bfloat16* __restrict__ s_table, int dst, int lane,
    float A0, float A1x, float A1y, float A1z,
    float A2x, float A2y, float A2z, float A3)
{
    if (dst < 0) return;
    __hip_bfloat16* srow = s_table + (size_t)dst * 384;
    float B0  = __shfl_down(A0, 1);
    float B1x = __shfl_down(A1x, 1);
    float B1y = __shfl_down(A1y, 1);
    float B1z = __shfl_down(A1z, 1);
    float B2x = __shfl_down(A2x, 1);
    float B2y = __shfl_down(A2y, 1);
    float B2z = __shfl_down(A2z, 1);
    float B3  = __shfl_down(A3, 1);
    if ((lane & 1) == 0) {
        pk_atomic_bf16(srow + lane,        pack_bf2(A0, B0));
        pk_atomic_bf16(srow + 64 + lane,   pack_bf2(A1x, B1x));
        pk_atomic_bf16(srow + 128 + lane,  pack_bf2(A1y, B1y));
        pk_atomic_bf16(srow + 192 + lane,  pack_bf2(A1z, B1z));
        if (lane < 32) {
            pk_atomic_bf16(srow + 256 + lane, pack_bf2(A2x, B2x));
            pk_atomic_bf16(srow + 288 + lane, pack_bf2(A2y, B2y));
            pk_atomic_bf16(srow + 320 + lane, pack_bf2(A2z, B2z));
            pk_atomic_bf16(srow + 352 + lane, pack_bf2(A3, B3));
        }
    }
}

// ---------------------------------------------------------------------------
// Kernel 2: edge kernel over SORTED edges.
// R7 = R6 register pipeline, but the per-tile sync points are real s_barriers
// (lgkmcnt-only, no vmcnt drain) instead of bare lgkmcnt fences:
//  * per-wave disjoint sHW regions (h and w of a wave share one 3200-short
//    region; no cross-wave overlap -> phase1->2 barrier not needed at all).
//  * 3 barriers/tile, each WITHOUT the vmcnt(0) drain __syncthreads forces,
//    so pk-bf16 atomics and l_table gathers stay in flight across them.
//  * phase-3 l_table gathers register-prefetched 16-deep before the GEMM.
//  * next tile's sorted_idx/el/metadata prefetched into registers.
//  * sW1 transposed [k][b] stride 16 -> phase-0 reads 5 dwords per column.
// ---------------------------------------------------------------------------
template <class T>
__device__ __forceinline__ void edge_body(
    const T* __restrict__ edge_attr, const T* __restrict__ el,
    const T* __restrict__ W_fc1, const T* __restrict__ W_fc2,
    const int* __restrict__ edge_src, const int* __restrict__ edge_dst,
    const int* __restrict__ sorted_idx,
    const T* __restrict__ l_table, __hip_bfloat16* __restrict__ s_table,
    __hip_bfloat16* sW1T, short* sW2B, short* sHW,
    int* sSrc, int* sDst, float* sAttr)
{
    __hip_bfloat16* sHWb = reinterpret_cast<__hip_bfloat16*>(sHW);
    const int tid = threadIdx.x;
    const int lane = tid & 63;
    const int wid = tid >> 6;
    const int quad = lane >> 4;
    const int m16 = lane & 15;
    const int wb16 = wid * 16;          // first edge-slot of this wave
    const int whw = wid * WAVE_HW;      // this wave's sHW region (shorts)

    // ---- one-time weight staging
    for (int i = tid; i < NBASIS * NRADIAL; i += 256) {
        int k = i / NBASIS, b = i - k * NBASIS;
        sW1T[k * 16 + b] = __float2bfloat16(ldv(W_fc1, (size_t)b * NRADIAL + k));
    }
    for (int i = tid; i < 12 * 4 * 64 * 8; i += 256) {
        int j = i & 7, ln = (i >> 3) & 63, kt = (i >> 9) & 3, t = i >> 11;
        int k = kt * 32 + ((ln >> 4) * 8) + j;
        int n = t * 16 + (ln & 15);
        reinterpret_cast<__hip_bfloat16*>(sW2B)[i] =
            (k < NRADIAL) ? __float2bfloat16(ldv(W_fc2, (size_t)k * WNUMEL + n))
                          : __float2bfloat16(0.f);
    }
    __syncthreads();

    const int e0r = tid >> 2;     // phase0 edge row (0..63)
    const int part = tid & 3;     // phase0 k-quarter
    const int hbase = (e0r >> 4) * WAVE_HW + (e0r & 15) * HSTRIDE;

    // ---- prologue: prefetch first tile's eg / elv / metadata into registers
    int tile = blockIdx.x;
    int eg = sorted_idx[tile * 64 + e0r];
    float elv[NBASIS];
#pragma unroll
    for (int b = 0; b < NBASIS; ++b) elv[b] = ldv(el, (size_t)eg * NBASIS + b);
    int mi = 0; float ma = 0.f, mb = 0.f;
    if (part == 0)      mi = edge_src[eg];
    else if (part == 1) mi = edge_dst[eg];
    else if (part == 2) { ma = ldv(edge_attr, (size_t)eg * 4 + 0); mb = ldv(edge_attr, (size_t)eg * 4 + 1); }
    else                { ma = ldv(edge_attr, (size_t)eg * 4 + 2); mb = ldv(edge_attr, (size_t)eg * 4 + 3); }

    for (; tile < NTILES; tile += gridDim.x) {
        // ---- metadata stage (registers -> LDS)
        if (part == 0)      sSrc[e0r] = mi;
        else if (part == 1) sDst[e0r] = mi;
        else if (part == 2) { sAttr[e0r * 4 + 0] = ma; sAttr[e0r * 4 + 1] = mb; }
        else                { sAttr[e0r * 4 + 2] = ma; sAttr[e0r * 4 + 3] = mb; }

        // ---- phase 0: layer-1 MLP from register elv
        {
            const float HS = 0.04472135954999579f;   // sqrt(2)/sqrt(10)*0.1
            for (int kk = 0; kk < 25; ++kk) {
                int k = part * 25 + kk;
                const unsigned int* wp = (const unsigned int*)&sW1T[k * 16];
                float z = 0.f;
#pragma unroll
                for (int b2 = 0; b2 < 5; ++b2) {
                    unsigned int w2 = wp[b2];
                    __hip_bfloat162 hw;
                    __builtin_memcpy(&hw, &w2, 4);
                    z += elv[2 * b2] * b2f(hw.x) + elv[2 * b2 + 1] * b2f(hw.y);
                }
                sHWb[hbase + k] = __float2bfloat16(fmaxf(z, 0.f) * HS);
            }
            for (int k = 100 + part * 7; k < 107 + part * 7; ++k)   // pad 100..127
                sHWb[hbase + k] = __float2bfloat16(0.f);
        }

        // ---- issue next tile's sorted_idx load (consumed after the GEMM)
        int ntile = tile + (int)gridDim.x;
        int negi = (ntile < NTILES) ? ntile : tile;     // clamp to valid row
        int next_eg = sorted_idx[negi * 64 + e0r];

        sync_lds();   // h + metadata writes visible; no vmcnt drain

        // ---- phase 1: A-fragment loads (wave's 16 edges)
        short8 afrag[4];
#pragma unroll
        for (int kt = 0; kt < 4; ++kt)
            afrag[kt] = *(const short8*)&sHW[whw + m16 * HSTRIDE + kt * 32 + quad * 8];

        // ---- phase-3 gather prefetch: 16-deep l_table reads fly during the GEMM
        int srcs[16];
#pragma unroll
        for (int i = 0; i < 16; ++i) srcs[i] = sSrc[wb16 + i];
        float y0p[16];
        float y1p[16][3];
#pragma unroll
        for (int i = 0; i < 16; ++i)
            y0p[i] = ldv(l_table + (size_t)srcs[i] * 160, lane);
        if (lane < 32) {
#pragma unroll
            for (int i = 0; i < 16; ++i) {
                const T* lrow = l_table + (size_t)srcs[i] * 160 + 64 + lane * 3;
                y1p[i][0] = ldv(lrow, 0);
                y1p[i][1] = ldv(lrow, 1);
                y1p[i][2] = ldv(lrow, 2);
            }
        }

        // ---- phase 2: GEMM w = h @ W2, C (bf16) into this wave's sHW rows
        // (no barrier needed between phase 1 and 2: h/w unions are per-wave)
#pragma unroll
        for (int t = 0; t < 12; ++t) {
            f32x4 acc = {0.f, 0.f, 0.f, 0.f};
#pragma unroll
            for (int kt = 0; kt < 4; ++kt) {
                short8 bfrag = *(const short8*)&sW2B[(((t * 4) + kt) * 64 + lane) * 8];
                acc = __builtin_amdgcn_mfma_f32_16x16x32_bf16(afrag[kt], bfrag, acc, 0, 0, 0);
            }
#pragma unroll
            for (int r = 0; r < 4; ++r)
                sHWb[whw + (quad * 4 + r) * WSTRIDE + t * 16 + m16] = __float2bfloat16(acc[r]);
        }

        // ---- issue next tile's elv / metadata loads (hidden under phase 3)
        float elvN[NBASIS]; int miN = 0; float maN = 0.f, mbN = 0.f;
#pragma unroll
        for (int b = 0; b < NBASIS; ++b) elvN[b] = ldv(el, (size_t)next_eg * NBASIS + b);
        if (part == 0)      miN = edge_src[next_eg];
        else if (part == 1) miN = edge_dst[next_eg];
        else if (part == 2) { maN = ldv(edge_attr, (size_t)next_eg * 4 + 0); mbN = ldv(edge_attr, (size_t)next_eg * 4 + 1); }
        else                { maN = ldv(edge_attr, (size_t)next_eg * 4 + 2); mbN = ldv(edge_attr, (size_t)next_eg * 4 + 3); }

        sync_lds();   // w writes visible; no vmcnt drain

        // ---- phase 3: run-aggregated messages + pk-bf16 atomic scatter
        float A0 = 0.f, A1x = 0.f, A1y = 0.f, A1z = 0.f;
        float A2x = 0.f, A2y = 0.f, A2z = 0.f, A3 = 0.f;
        int cur_dst = -1;
#pragma unroll
        for (int i = 0; i < 16; ++i) {
            int elc = wb16 + i;
            int dst = sDst[elc];                   // wave-uniform (LDS)
            if (dst != cur_dst) {
                flush_acc(s_table, cur_dst, lane, A0, A1x, A1y, A1z, A2x, A2y, A2z, A3);
                A0 = A1x = A1y = A1z = A2x = A2y = A2z = A3 = 0.f;
                cur_dst = dst;
            }
            float e0  = sAttr[elc * 4 + 0];
            float e1x = sAttr[elc * 4 + 1];
            float e1y = sAttr[elc * 4 + 2];
            float e1z = sAttr[elc * 4 + 3];

            int wrow = whw + i * WSTRIDE;
            float y0 = y0p[i];
            float w_a = b2f(sHWb[wrow + lane]);
            float w_b = b2f(sHWb[wrow + 64 + lane]);

            A0 += w_a * y0 * e0;                       // m0
            float m1b = w_b * y0;                      // m1
            A1x += m1b * e1x; A1y += m1b * e1y; A1z += m1b * e1z;
            if (lane < 32) {
                float w_c = b2f(sHWb[wrow + 128 + lane]);
                float w3v = b2f(sHWb[wrow + 160 + lane]);
                float g = w_c * e0;                    // m2
                A2x += g * y1p[i][0]; A2y += g * y1p[i][1]; A2z += g * y1p[i][2];
                float dot = y1p[i][0] * e1x + y1p[i][1] * e1y + y1p[i][2] * e1z;
                A3 += w3v * dot * 0.5773502691896258f; // m3
            }
        }
        flush_acc(s_table, cur_dst, lane, A0, A1x, A1y, A1z, A2x, A2y, A2z, A3);

        // ---- rotate software pipeline registers
        eg = next_eg;
#pragma unroll
        for (int b = 0; b < NBASIS; ++b) elv[b] = elvN[b];
        mi = miN; ma = maN; mb = mbN;

        sync_lds();   // this tile's LDS reads done before next tile's writes
    }
    asm volatile("s_waitcnt vmcnt(0)" ::: "memory");   // drain asm atomics
}

__global__ __launch_bounds__(256) void edge_kernel(
    const void* edge_attr, const void* el, const void* W_fc1, const void* W_fc2,
    const int* edge_src, const int* edge_dst, const int* sorted_idx,
    const void* l_table, __hip_bfloat16* s_table, const void* node_attr)
{
    __shared__ __hip_bfloat16 sW1T[NRADIAL * 16];      // 3200 B (transposed, stride 16)
    __shared__ short sW2B[12 * 4 * 64 * 8];            // 49152 B
    __shared__ short sHW[64 * WSTRIDE];                // 25600 B (per-wave h/w union)
    __shared__ int sSrc[64], sDst[64];                 // 512 B
    __shared__ float sAttr[256];                       // 1024 B
    if (input_is_f32(node_attr))
        edge_body<float>((const float*)edge_attr, (const float*)el,
                         (const float*)W_fc1, (const float*)W_fc2,
                         edge_src, edge_dst, sorted_idx,
                         (const float*)l_table, s_table,
                         sW1T, sW2B, sHW, sSrc, sDst, sAttr);
    else
        edge_body<__hip_bfloat16>((const __hip_bfloat16*)edge_attr,
                                  (const __hip_bfloat16*)el,
                                  (const __hip_bfloat16*)W_fc1,
                                  (const __hip_bfloat16*)W_fc2,
                                  edge_src, edge_dst, sorted_idx,
                                  (const __hip_bfloat16*)l_table, s_table,
                                  sW1T, sW2B, sHW, sSrc, sDst, sAttr);
}

// ---------------------------------------------------------------------------
// Kernel 3: output. Per-node W_l2 mixes of bf16 s_table + self-interaction.
// ---------------------------------------------------------------------------
template <class T>
__device__ __forceinline__ void output_body(
    const T* __restrict__ node_input, const T* __restrict__ node_attr,
    const T* __restrict__ W_si0, const T* __restrict__ W_si1,
    const T* __restrict__ W_l2_00, const T* __restrict__ W_l2_10,
    const T* __restrict__ W_l2_01, const T* __restrict__ W_l2_11,
    const __hip_bfloat16* __restrict__ s_table, T* __restrict__ out)
{
    int wave = (blockIdx.x * 256 + threadIdx.x) >> 6;
    int lane = threadIdx.x & 63;
    if (wave >= N_NODES) return;
    const int n = wave;
    float a = ldv(node_attr, n);
    const T* xrow = node_input + (size_t)n * 160;
    const __hip_bfloat16* srow = s_table + (size_t)n * 384;

    float si = 0.f, o = 0.f;
    for (int u = 0; u < 64; ++u) {
        si += ldv(xrow, u) * ldv(W_si0, u * 64 + lane);
        o += b2f(srow[u]) * ldv(W_l2_00, u * 64 + lane);
    }
    for (int u = 0; u < 32; ++u)
        o += b2f(srow[352 + u]) * ldv(W_l2_10, u * 64 + lane);

    // 0.5 (skip-mix) * 0.25 (1/sqrt(16)) / sqrt(96)
    const float OC = 0.5f * 0.25f / 9.797958971132712f;
    stv(out, (size_t)n * 160 + lane, si * a * 0.125f + o * a * OC);

    if (lane < 32) {
        float sid[3] = {0.f, 0.f, 0.f}, od[3] = {0.f, 0.f, 0.f};
        for (int u = 0; u < 32; ++u) {
            float wsi = ldv(W_si1, u * 32 + lane);
            float wl2 = ldv(W_l2_11, u * 32 + lane);
#pragma unroll
            for (int d = 0; d < 3; ++d) {
                sid[d] += ldv(xrow, 64 + u * 3 + d) * wsi;
                od[d] += b2f(srow[256 + d * 32 + u]) * wl2;   // s2 planes
            }
        }
        for (int u = 0; u < 64; ++u) {
            float wl2 = ldv(W_l2_01, u * 32 + lane);
#pragma unroll
            for (int d = 0; d < 3; ++d)
                od[d] += b2f(srow[64 + d * 64 + u]) * wl2;    // s1 planes
        }
        const float SI1 = a * 0.17677669529663687f;
#pragma unroll
        for (int d = 0; d < 3; ++d)
            stv(out, (size_t)n * 160 + 64 + lane * 3 + d, sid[d] * SI1 + od[d] * a * OC);
    }
}

__global__ __launch_bounds__(256) void output_kernel(
    const void* node_input, const void* node_attr,
    const void* W_si0, const void* W_si1,
    const void* W_l2_00, const void* W_l2_10,
    const void* W_l2_01, const void* W_l2_11,
    const __hip_bfloat16* s_table, void* out)
{
    if (input_is_f32(node_attr))
        output_body<float>((const float*)node_input, (const float*)node_attr,
                           (const float*)W_si0, (const float*)W_si1,
                           (const float*)W_l2_00, (const float*)W_l2_10,
                           (const float*)W_l2_01, (const float*)W_l2_11,
                           s_table, (float*)out);
    else
        output_body<__hip_bfloat16>((const __hip_bfloat16*)node_input,
                                    (const __hip_bfloat16*)node_attr,
                                    (const __hip_bfloat16*)W_si0,
                                    (const __hip_bfloat16*)W_si1,
                                    (const __hip_bfloat16*)W_l2_00,
                                    (const __hip_bfloat16*)W_l2_10,
                                    (const __hip_bfloat16*)W_l2_01,
                                    (const __hip_bfloat16*)W_l2_11,
                                    s_table, (__hip_bfloat16*)out);
}

extern "C" void kernel_launch(void* const* d_in, const int* in_sizes, int n_in,
                              void* d_out, int out_size, void* d_ws, size_t ws_size,
                              hipStream_t stream)
{
    const void* node_input = d_in[0];
    const void* node_attr  = d_in[1];
    const void* edge_attr  = d_in[2];
    const void* el         = d_in[3];
    const void* W_si0  = d_in[4];
    const void* W_si1  = d_in[5];
    const void* W_l1_0 = d_in[6];
    const void* W_l1_1 = d_in[7];
    const void* W_l2_00 = d_in[8];
    const void* W_l2_10 = d_in[9];
    const void* W_l2_01 = d_in[10];
    const void* W_l2_11 = d_in[11];
    const void* W_fc1  = d_in[12];
    const void* W_fc2  = d_in[13];
    const int* edge_src = (const int*)d_in[14];
    const int* edge_dst = (const int*)d_in[15];

    // ws layout: s_table bf16 (N*384*2 = 38.4 MB) | sorted_idx (3.2 MB) | counts (0.2 MB)
    __hip_bfloat16* s_table = (__hip_bfloat16*)d_ws;
    int* sorted_idx = (int*)((char*)d_ws + (size_t)N_NODES * 384 * 2);
    int* counts     = (int*)((char*)sorted_idx + (size_t)N_EDGES * 4);
    void* l_table = d_out;   // N*160 elements, overwritten by output_kernel

    size_t ws_used = (size_t)N_NODES * 384 * 2 + (size_t)N_EDGES * 4 + (size_t)N_NODES * 4;
    hipMemsetAsync(d_ws, 0, ws_used, stream);

    hist_kernel<<<(N_EDGES + 255) / 256, 256, 0, stream>>>(edge_dst, counts);
    scan_kernel<<<1, 1024, 0, stream>>>(counts);
    scatter_kernel<<<(N_EDGES + 255) / 256, 256, 0, stream>>>(edge_dst, counts, sorted_idx);

    node_linear_kernel<<<(N_NODES + 3) / 4, 256, 0, stream>>>(
        node_input, node_attr, W_l1_0, W_l1_1, l_table);
    edge_kernel<<<EDGE_GRID, 256, 0, stream>>>(
        edge_attr, el, W_fc1, W_fc2, edge_src, edge_dst, sorted_idx,
        l_table, s_table, node_attr);
    output_kernel<<<(N_NODES + 3) / 4, 256, 0, stream>>>(
        node_input, node_attr, W_si0, W_si1, W_l2_00, W_l2_10, W_l2_01, W_l2_11,
        s_table, d_out);
}

// Round 6
// 1007.338 us; speedup vs baseline: 1.2308x; 1.0037x over previous
//
#include <hip/hip_runtime.h>
#include <hip/hip_bf16.h>

#define N_NODES 50000
#define N_EDGES 800000
#define NBASIS 10
#define NRADIAL 100
#define WNUMEL 192
#define OTILES 3125           // 50000 / 16, exact (node tiles for MFMA kernels)
#define EDGE_GRID 500         // 500 blocks x 4 waves = 2000 waves
#define WPW 25                // 16-edge windows per wave; 2000*25*16 = 800000 exact
#define NODE_GRID 512
#define HSTRIDE 136           // shorts per h-row (128 + 8 pad)
#define WSTRIDE 200           // shorts per w-row (192 + 8 pad)
#define WAVE_HW 3200          // shorts per wave region of sHW
// s_table: bf16, 384 per node, plane layout:
// [0:64]=s0 | [64:128]=s1x [128:192]=s1y [192:256]=s1z
// [256:288]=s2x [288:320]=s2y [320:352]=s2z | [352:384]=s3

typedef __attribute__((ext_vector_type(8))) short short8;
typedef __attribute__((ext_vector_type(4))) float f32x4;

__device__ __forceinline__ float b2f(__hip_bfloat16 x) { return __bfloat162float(x); }
__device__ __forceinline__ float ldv(const float* p, size_t i) { return p[i]; }
__device__ __forceinline__ float ldv(const __hip_bfloat16* p, size_t i) { return b2f(p[i]); }

__device__ __forceinline__ bool input_is_f32(const void* node_attr) {
    return ((const unsigned short*)node_attr)[0] == 0;   // bf16(1.0)=0x3F80
}

__device__ __forceinline__ unsigned int pack_bf2(float x, float y) {
    __hip_bfloat162 h;
    h.x = __float2bfloat16(x);
    h.y = __float2bfloat16(y);
    unsigned int u;
    __builtin_memcpy(&u, &h, 4);
    return u;
}

__device__ __forceinline__ void pk_atomic_bf16(__hip_bfloat16* addr, unsigned int data) {
    asm volatile("global_atomic_pk_add_bf16 %0, %1, off"
                 :: "v"((unsigned long long)(uintptr_t)addr), "v"(data)
                 : "memory");
}

// __syncthreads() minus the vmcnt(0) drain.
__device__ __forceinline__ void sync_lds() {
    asm volatile("s_waitcnt lgkmcnt(0)" ::: "memory");
    __builtin_amdgcn_s_barrier();
}

// ---------------------------------------------------------------------------
// Sort kernels: counting sort of edges by dst + stabilizing segment sort.
// ---------------------------------------------------------------------------
__global__ __launch_bounds__(256) void hist_kernel(const int* __restrict__ edge_dst,
                                                   int* __restrict__ counts) {
    int i = blockIdx.x * 256 + threadIdx.x;
    if (i < N_EDGES) atomicAdd(&counts[edge_dst[i]], 1);
}

__global__ __launch_bounds__(1024) void scan_kernel(int* __restrict__ counts) {
    __shared__ int lsum[1024];
    int t = threadIdx.x;
    int lo = t * 49;
    int hi = min(lo + 49, N_NODES);
    int s = 0;
    for (int i = lo; i < hi; ++i) s += counts[i];
    lsum[t] = s;
    __syncthreads();
    for (int off = 1; off < 1024; off <<= 1) {
        int add = (t >= off) ? lsum[t - off] : 0;
        __syncthreads();
        lsum[t] += add;
        __syncthreads();
    }
    int running = lsum[t] - s;   // exclusive prefix
    for (int i = lo; i < hi; ++i) { int c = counts[i]; counts[i] = running; running += c; }
}

__global__ __launch_bounds__(256) void scatter_kernel(const int* __restrict__ edge_dst,
                                                      int* __restrict__ counts,
                                                      int* __restrict__ sorted_idx) {
    int i = blockIdx.x * 256 + threadIdx.x;
    if (i < N_EDGES) {
        int p = atomicAdd(&counts[edge_dst[i]], 1);
        sorted_idx[p] = i;
    }
}

// Stable order within each dst segment -> deterministic edge order every run
// (scatter's atomicAdd tie-order is timing-dependent). After scatter,
// counts[n] == end of segment n.
__global__ __launch_bounds__(256) void segsort_kernel(const int* __restrict__ counts,
                                                      int* __restrict__ sorted_idx) {
    int n = blockIdx.x * 256 + threadIdx.x;
    if (n >= N_NODES) return;
    int start = (n == 0) ? 0 : counts[n - 1];
    int end = counts[n];
    for (int i = start + 1; i < end; ++i) {
        int v = sorted_idx[i];
        int j = i - 1;
        while (j >= start && sorted_idx[j] > v) { sorted_idx[j + 1] = sorted_idx[j]; --j; }
        sorted_idx[j + 1] = v;
    }
}

// ---------------------------------------------------------------------------
// Kernel 1 (f32 fallback): scalar per-node linear, grid-stride over nodes.
// ---------------------------------------------------------------------------
__device__ __forceinline__ void node_linear_f32(
    const float* __restrict__ node_input, const float* __restrict__ node_attr,
    const float* __restrict__ W_l1_0, const float* __restrict__ W_l1_1,
    float* __restrict__ l_table)
{
    int gw = (blockIdx.x * 256 + threadIdx.x) >> 6;
    int nwv = (gridDim.x * 256) >> 6;
    int lane = threadIdx.x & 63;
    for (int n = gw; n < N_NODES; n += nwv) {
        float a = node_attr[n];
        const float* xrow = node_input + (size_t)n * 160;

        float acc = 0.f;
        for (int u = 0; u < 64; ++u)
            acc += xrow[u] * W_l1_0[u * 64 + lane];
        l_table[(size_t)n * 160 + lane] = acc * a * 0.125f;

        if (lane < 32) {
            float a0 = 0.f, a1 = 0.f, a2 = 0.f;
            for (int u = 0; u < 32; ++u) {
                float wv = W_l1_1[u * 32 + lane];
                a0 += xrow[64 + u * 3 + 0] * wv;
                a1 += xrow[64 + u * 3 + 1] * wv;
                a2 += xrow[64 + u * 3 + 2] * wv;
            }
            const float s = a * 0.17677669529663687f;
            l_table[(size_t)n * 160 + 64 + lane * 3 + 0] = a0 * s;
            l_table[(size_t)n * 160 + 64 + lane * 3 + 1] = a1 * s;
            l_table[(size_t)n * 160 + 64 + lane * 3 + 2] = a2 * s;
        }
    }
}

// ---------------------------------------------------------------------------
// Kernel 1 (bf16): MFMA (layout validated on HW in R9's initial check).
// ---------------------------------------------------------------------------
__device__ __forceinline__ void node_linear_mfma(
    const short* __restrict__ ni, const __hip_bfloat16* __restrict__ na,
    const short* __restrict__ W0, const short* __restrict__ W1,
    __hip_bfloat16* __restrict__ lt, short* sB0, short* sB1)
{
    const int tid = threadIdx.x;
    const int lane = tid & 63;
    const int wid = tid >> 6;
    const int quad = lane >> 4;
    const int m16 = lane & 15;

    for (int i = tid; i < 8 * 512; i += 256) {
        int j = i & 7, ln = (i >> 3) & 63, f = i >> 9;
        int kt = f & 1, ct = f >> 1;
        int k = kt * 32 + ((ln >> 4) << 3) + j;
        int col = ct * 16 + (ln & 15);
        sB0[i] = W0[k * 64 + col];
    }
    for (int i = tid; i < 2 * 512; i += 256) {
        int j = i & 7, ln = (i >> 3) & 63, ct = i >> 9;
        int k = ((ln >> 4) << 3) + j;
        int col = ct * 16 + (ln & 15);
        sB1[i] = W1[k * 32 + col];
    }
    __syncthreads();

    int gw = blockIdx.x * 4 + wid;
    int nwv = gridDim.x * 4;
    for (int tile = gw; tile < OTILES; tile += nwv) {
        int tb = tile * 16;
        const short* arow = ni + (size_t)(tb + m16) * 160;

        short8 a0[2];
        a0[0] = *(const short8*)(arow + quad * 8);
        a0[1] = *(const short8*)(arow + 32 + quad * 8);

        f32x4 acc0[4];
#pragma unroll
        for (int ct = 0; ct < 4; ++ct) {
            f32x4 acc = {0.f, 0.f, 0.f, 0.f};
            acc = __builtin_amdgcn_mfma_f32_16x16x32_bf16(
                a0[0], *(const short8*)&sB0[(ct * 2 + 0) * 512 + lane * 8], acc, 0, 0, 0);
            acc = __builtin_amdgcn_mfma_f32_16x16x32_bf16(
                a0[1], *(const short8*)&sB0[(ct * 2 + 1) * 512 + lane * 8], acc, 0, 0, 0);
            acc0[ct] = acc;
        }

        f32x4 acc1[3][2];
#pragma unroll
        for (int d = 0; d < 3; ++d) {
            short8 a1;
#pragma unroll
            for (int j = 0; j < 8; ++j)
                a1[j] = arow[64 + (quad * 8 + j) * 3 + d];
#pragma unroll
            for (int ct = 0; ct < 2; ++ct) {
                f32x4 acc = {0.f, 0.f, 0.f, 0.f};
                acc = __builtin_amdgcn_mfma_f32_16x16x32_bf16(
                    a1, *(const short8*)&sB1[ct * 512 + lane * 8], acc, 0, 0, 0);
                acc1[d][ct] = acc;
            }
        }

        float an[4];
#pragma unroll
        for (int r = 0; r < 4; ++r) an[r] = b2f(na[tb + quad * 4 + r]);

#pragma unroll
        for (int ct = 0; ct < 4; ++ct)
#pragma unroll
            for (int r = 0; r < 4; ++r)
                lt[(size_t)(tb + quad * 4 + r) * 160 + ct * 16 + m16] =
                    __float2bfloat16(acc0[ct][r] * an[r] * 0.125f);
#pragma unroll
        for (int d = 0; d < 3; ++d)
#pragma unroll
            for (int ct = 0; ct < 2; ++ct)
#pragma unroll
                for (int r = 0; r < 4; ++r)
                    lt[(size_t)(tb + quad * 4 + r) * 160 + 64 + (ct * 16 + m16) * 3 + d] =
                        __float2bfloat16(acc1[d][ct][r] * an[r] * 0.17677669529663687f);
    }
}

__global__ __launch_bounds__(256) void node_linear_kernel(
    const void* node_input, const void* node_attr,
    const void* W_l1_0, const void* W_l1_1, void* l_table)
{
    __shared__ __attribute__((aligned(16))) short sB0[8 * 512];   // 8 KB
    __shared__ __attribute__((aligned(16))) short sB1[2 * 512];   // 2 KB
    if (input_is_f32(node_attr))
        node_linear_f32((const float*)node_input, (const float*)node_attr,
                        (const float*)W_l1_0, (const float*)W_l1_1, (float*)l_table);
    else
        node_linear_mfma((const short*)node_input, (const __hip_bfloat16*)node_attr,
                         (const short*)W_l1_0, (const short*)W_l1_1,
                         (__hip_bfloat16*)l_table, sB0, sB1);
}

// ---------------------------------------------------------------------------
// flush: pk-bf16 atomic add of 8 accumulator components into s_table[dst].
// With chunk-contiguous runs each node gets exactly ONE flush (f32-exact sum,
// single bf16 rounding); wave-chunk-boundary nodes get two, and round(a+b) is
// order-independent for two adds onto a zeroed cell -> fully deterministic.
// ---------------------------------------------------------------------------
__device__ __forceinline__ void flush_acc(
    __hip_bfloat16* __restrict__ s_table, int dst, int lane,
    float A0, float A1x, float A1y, float A1z,
    float A2x, float A2y, float A2z, float A3)
{
    if (dst < 0) return;
    __hip_bfloat16* srow = s_table + (size_t)dst * 384;
    float B0  = __shfl_down(A0, 1);
    float B1x = __shfl_down(A1x, 1);
    float B1y = __shfl_down(A1y, 1);
    float B1z = __shfl_down(A1z, 1);
    float B2x = __shfl_down(A2x, 1);
    float B2y = __shfl_down(A2y, 1);
    float B2z = __shfl_down(A2z, 1);
    float B3  = __shfl_down(A3, 1);
    if ((lane & 1) == 0) {
        pk_atomic_bf16(srow + lane,        pack_bf2(A0, B0));
        pk_atomic_bf16(srow + 64 + lane,   pack_bf2(A1x, B1x));
        pk_atomic_bf16(srow + 128 + lane,  pack_bf2(A1y, B1y));
        pk_atomic_bf16(srow + 192 + lane,  pack_bf2(A1z, B1z));
        if (lane < 32) {
            pk_atomic_bf16(srow + 256 + lane, pack_bf2(A2x, B2x));
            pk_atomic_bf16(srow + 288 + lane, pack_bf2(A2y, B2y));
            pk_atomic_bf16(srow + 320 + lane, pack_bf2(A2z, B2z));
            pk_atomic_bf16(srow + 352 + lane, pack_bf2(A3, B3));
        }
    }
}

// ---------------------------------------------------------------------------
// Kernel 2: edge kernel. R11 change vs R7: each WAVE owns a CONTIGUOUS
// 400-edge chunk of the sorted list (25 x 16-edge windows) and carries the
// run accumulator across windows in registers -> one flush per node.
// Phase structure, barriers, and prefetch pipeline identical to R7.
// ---------------------------------------------------------------------------
template <class T>
__device__ __forceinline__ void edge_body(
    const T* __restrict__ edge_attr, const T* __restrict__ el,
    const T* __restrict__ W_fc1, const T* __restrict__ W_fc2,
    const int* __restrict__ edge_src, const int* __restrict__ edge_dst,
    const int* __restrict__ sorted_idx,
    const T* __restrict__ l_table, __hip_bfloat16* __restrict__ s_table,
    __hip_bfloat16* sW1T, short* sW2B, short* sHW,
    int* sSrc, int* sDst, float* sAttr)
{
    __hip_bfloat16* sHWb = reinterpret_cast<__hip_bfloat16*>(sHW);
    const int tid = threadIdx.x;
    const int lane = tid & 63;
    const int wid = tid >> 6;
    const int quad = lane >> 4;
    const int m16 = lane & 15;
    const int wb16 = wid * 16;
    const int whw = wid * WAVE_HW;

    for (int i = tid; i < NBASIS * NRADIAL; i += 256) {
        int k = i / NBASIS, b = i - k * NBASIS;
        sW1T[k * 16 + b] = __float2bfloat16(ldv(W_fc1, (size_t)b * NRADIAL + k));
    }
    for (int i = tid; i < 12 * 4 * 64 * 8; i += 256) {
        int j = i & 7, ln = (i >> 3) & 63, kt = (i >> 9) & 3, t = i >> 11;
        int k = kt * 32 + ((ln >> 4) * 8) + j;
        int n = t * 16 + (ln & 15);
        reinterpret_cast<__hip_bfloat16*>(sW2B)[i] =
            (k < NRADIAL) ? __float2bfloat16(ldv(W_fc2, (size_t)k * WNUMEL + n))
                          : __float2bfloat16(0.f);
    }
    __syncthreads();

    const int e0r = tid >> 2;       // row 0..63 (16 per wave)
    const int part = tid & 3;       // k-quarter of the row's MLP
    const int rwave = e0r >> 4;     // wave owning this row
    const int hbase = rwave * WAVE_HW + (e0r & 15) * HSTRIDE;
    // this row-thread's edge at window it: rbase + it*16
    const int rbase = (blockIdx.x * 4 + rwave) * (WPW * 16) + (e0r & 15);

    // ---- prologue: prefetch window 0's eg / elv / metadata
    int eg = sorted_idx[rbase];
    float elv[NBASIS];
#pragma unroll
    for (int b = 0; b < NBASIS; ++b) elv[b] = ldv(el, (size_t)eg * NBASIS + b);
    int mi = 0; float ma = 0.f, mb = 0.f;
    if (part == 0)      mi = edge_src[eg];
    else if (part == 1) mi = edge_dst[eg];
    else if (part == 2) { ma = ldv(edge_attr, (size_t)eg * 4 + 0); mb = ldv(edge_attr, (size_t)eg * 4 + 1); }
    else                { ma = ldv(edge_attr, (size_t)eg * 4 + 2); mb = ldv(edge_attr, (size_t)eg * 4 + 3); }

    // ---- carried phase-3 run state (persists across windows)
    float A0 = 0.f, A1x = 0.f, A1y = 0.f, A1z = 0.f;
    float A2x = 0.f, A2y = 0.f, A2z = 0.f, A3 = 0.f;
    int cur_dst = -1;

    for (int it = 0; it < WPW; ++it) {
        // ---- metadata stage (registers -> LDS)
        if (part == 0)      sSrc[e0r] = mi;
        else if (part == 1) sDst[e0r] = mi;
        else if (part == 2) { sAttr[e0r * 4 + 0] = ma; sAttr[e0r * 4 + 1] = mb; }
        else                { sAttr[e0r * 4 + 2] = ma; sAttr[e0r * 4 + 3] = mb; }

        // ---- phase 0: layer-1 MLP from register elv
        {
            const float HS = 0.04472135954999579f;
            for (int kk = 0; kk < 25; ++kk) {
                int k = part * 25 + kk;
                const unsigned int* wp = (const unsigned int*)&sW1T[k * 16];
                float z = 0.f;
#pragma unroll
                for (int b2 = 0; b2 < 5; ++b2) {
                    unsigned int w2 = wp[b2];
                    __hip_bfloat162 hw;
                    __builtin_memcpy(&hw, &w2, 4);
                    z += elv[2 * b2] * b2f(hw.x) + elv[2 * b2 + 1] * b2f(hw.y);
                }
                sHWb[hbase + k] = __float2bfloat16(fmaxf(z, 0.f) * HS);
            }
            for (int k = 100 + part * 7; k < 107 + part * 7; ++k)
                sHWb[hbase + k] = __float2bfloat16(0.f);
        }

        // ---- issue next window's sorted_idx load
        int nit = (it + 1 < WPW) ? it + 1 : it;
        int next_eg = sorted_idx[rbase + nit * 16];

        sync_lds();

        // ---- phase 1: A-fragment loads (wave's 16 edges)
        short8 afrag[4];
#pragma unroll
        for (int kt = 0; kt < 4; ++kt)
            afrag[kt] = *(const short8*)&sHW[whw + m16 * HSTRIDE + kt * 32 + quad * 8];

        // ---- phase-3 gather prefetch: 16-deep l_table reads fly during GEMM
        int srcs[16];
#pragma unroll
        for (int i = 0; i < 16; ++i) srcs[i] = sSrc[wb16 + i];
        float y0p[16];
        float y1p[16][3];
#pragma unroll
        for (int i = 0; i < 16; ++i)
            y0p[i] = ldv(l_table + (size_t)srcs[i] * 160, lane);
        if (lane < 32) {
#pragma unroll
            for (int i = 0; i < 16; ++i) {
                const T* lrow = l_table + (size_t)srcs[i] * 160 + 64 + lane * 3;
                y1p[i][0] = ldv(lrow, 0);
                y1p[i][1] = ldv(lrow, 1);
                y1p[i][2] = ldv(lrow, 2);
            }
        }

        // ---- phase 2: GEMM w = h @ W2 into this wave's sHW rows
#pragma unroll
        for (int t = 0; t < 12; ++t) {
            f32x4 acc = {0.f, 0.f, 0.f, 0.f};
#pragma unroll
            for (int kt = 0; kt < 4; ++kt) {
                short8 bfrag = *(const short8*)&sW2B[(((t * 4) + kt) * 64 + lane) * 8];
                acc = __builtin_amdgcn_mfma_f32_16x16x32_bf16(afrag[kt], bfrag, acc, 0, 0, 0);
            }
#pragma unroll
            for (int r = 0; r < 4; ++r)
                sHWb[whw + (quad * 4 + r) * WSTRIDE + t * 16 + m16] = __float2bfloat16(acc[r]);
        }

        // ---- issue next window's elv / metadata loads (hidden under phase 3)
        float elvN[NBASIS]; int miN = 0; float maN = 0.f, mbN = 0.f;
#pragma unroll
        for (int b = 0; b < NBASIS; ++b) elvN[b] = ldv(el, (size_t)next_eg * NBASIS + b);
        if (part == 0)      miN = edge_src[next_eg];
        else if (part == 1) miN = edge_dst[next_eg];
        else if (part == 2) { maN = ldv(edge_attr, (size_t)next_eg * 4 + 0); mbN = ldv(edge_attr, (size_t)next_eg * 4 + 1); }
        else                { maN = ldv(edge_attr, (size_t)next_eg * 4 + 2); mbN = ldv(edge_attr, (size_t)next_eg * 4 + 3); }

        sync_lds();

        // ---- phase 3: run-aggregated messages, accumulator carried across it
#pragma unroll
        for (int i = 0; i < 16; ++i) {
            int elc = wb16 + i;
            int dst = sDst[elc];
            if (dst != cur_dst) {
                flush_acc(s_table, cur_dst, lane, A0, A1x, A1y, A1z, A2x, A2y, A2z, A3);
                A0 = A1x = A1y = A1z = A2x = A2y = A2z = A3 = 0.f;
                cur_dst = dst;
            }
            float e0  = sAttr[elc * 4 + 0];
            float e1x = sAttr[elc * 4 + 1];
            float e1y = sAttr[elc * 4 + 2];
            float e1z = sAttr[elc * 4 + 3];

            int wrow = whw + i * WSTRIDE;
            float y0 = y0p[i];
            float w_a = b2f(sHWb[wrow + lane]);
            float w_b = b2f(sHWb[wrow + 64 + lane]);

            A0 += w_a * y0 * e0;
            float m1b = w_b * y0;
            A1x += m1b * e1x; A1y += m1b * e1y; A1z += m1b * e1z;
            if (lane < 32) {
                float w_c = b2f(sHWb[wrow + 128 + lane]);
                float w3v = b2f(sHWb[wrow + 160 + lane]);
                float g = w_c * e0;
                A2x += g * y1p[i][0]; A2y += g * y1p[i][1]; A2z += g * y1p[i][2];
                float dot = y1p[i][0] * e1x + y1p[i][1] * e1y + y1p[i][2] * e1z;
                A3 += w3v * dot * 0.5773502691896258f;
            }
        }

        // ---- rotate software pipeline registers
        eg = next_eg;
#pragma unroll
        for (int b = 0; b < NBASIS; ++b) elv[b] = elvN[b];
        mi = miN; ma = maN; mb = mbN;

        sync_lds();
    }
    // final flush of the carried run
    flush_acc(s_table, cur_dst, lane, A0, A1x, A1y, A1z, A2x, A2y, A2z, A3);
    asm volatile("s_waitcnt vmcnt(0)" ::: "memory");
}

__global__ __launch_bounds__(256) void edge_kernel(
    const void* edge_attr, const void* el, const void* W_fc1, const void* W_fc2,
    const int* edge_src, const int* edge_dst, const int* sorted_idx,
    const void* l_table, __hip_bfloat16* s_table, const void* node_attr)
{
    __shared__ __hip_bfloat16 sW1T[NRADIAL * 16];
    __shared__ short sW2B[12 * 4 * 64 * 8];
    __shared__ short sHW[64 * WSTRIDE];
    __shared__ int sSrc[64], sDst[64];
    __shared__ float sAttr[256];
    if (input_is_f32(node_attr))
        edge_body<float>((const float*)edge_attr, (const float*)el,
                         (const float*)W_fc1, (const float*)W_fc2,
                         edge_src, edge_dst, sorted_idx,
                         (const float*)l_table, s_table,
                         sW1T, sW2B, sHW, sSrc, sDst, sAttr);
    else
        edge_body<__hip_bfloat16>((const __hip_bfloat16*)edge_attr,
                                  (const __hip_bfloat16*)el,
                                  (const __hip_bfloat16*)W_fc1,
                                  (const __hip_bfloat16*)W_fc2,
                                  edge_src, edge_dst, sorted_idx,
                                  (const __hip_bfloat16*)l_table, s_table,
                                  sW1T, sW2B, sHW, sSrc, sDst, sAttr);
}

// ---------------------------------------------------------------------------
// Kernel 3 (f32 fallback): scalar output, bf16 s_table.
// ---------------------------------------------------------------------------
__device__ __forceinline__ void output_f32(
    const float* __restrict__ node_input, const float* __restrict__ node_attr,
    const float* __restrict__ W_si0, const float* __restrict__ W_si1,
    const float* __restrict__ W_l2_00, const float* __restrict__ W_l2_10,
    const float* __restrict__ W_l2_01, const float* __restrict__ W_l2_11,
    const __hip_bfloat16* __restrict__ s_table, float* __restrict__ out)
{
    int gw = (blockIdx.x * 256 + threadIdx.x) >> 6;
    int nwv = (gridDim.x * 256) >> 6;
    int lane = threadIdx.x & 63;
    for (int n = gw; n < N_NODES; n += nwv) {
        float a = node_attr[n];
        const float* xrow = node_input + (size_t)n * 160;
        const __hip_bfloat16* srow = s_table + (size_t)n * 384;

        float si = 0.f, o = 0.f;
        for (int u = 0; u < 64; ++u) {
            si += xrow[u] * W_si0[u * 64 + lane];
            o += b2f(srow[u]) * W_l2_00[u * 64 + lane];
        }
        for (int u = 0; u < 32; ++u)
            o += b2f(srow[352 + u]) * W_l2_10[u * 64 + lane];

        const float OC = 0.5f * 0.25f / 9.797958971132712f;
        out[(size_t)n * 160 + lane] = si * a * 0.125f + o * a * OC;

        if (lane < 32) {
            float sid[3] = {0.f, 0.f, 0.f}, od[3] = {0.f, 0.f, 0.f};
            for (int u = 0; u < 32; ++u) {
                float wsi = W_si1[u * 32 + lane];
                float wl2 = W_l2_11[u * 32 + lane];
#pragma unroll
                for (int d = 0; d < 3; ++d) {
                    sid[d] += xrow[64 + u * 3 + d] * wsi;
                    od[d] += b2f(srow[256 + d * 32 + u]) * wl2;
                }
            }
            for (int u = 0; u < 64; ++u) {
                float wl2 = W_l2_01[u * 32 + lane];
#pragma unroll
                for (int d = 0; d < 3; ++d)
                    od[d] += b2f(srow[64 + d * 64 + u]) * wl2;
            }
            const float SI1 = a * 0.17677669529663687f;
#pragma unroll
            for (int d = 0; d < 3; ++d)
                out[(size_t)n * 160 + 64 + lane * 3 + d] = sid[d] * SI1 + od[d] * a * OC;
        }
    }
}

// ---------------------------------------------------------------------------
// Kernel 3 (bf16): MFMA with dual accumulators (HW-validated in R9).
// ---------------------------------------------------------------------------
__device__ __forceinline__ void output_mfma(
    const short* __restrict__ ni, const __hip_bfloat16* __restrict__ na,
    const short* __restrict__ Wsi0, const short* __restrict__ Wsi1,
    const short* __restrict__ W00, const short* __restrict__ W10,
    const short* __restrict__ W01, const short* __restrict__ W11,
    const short* __restrict__ st, __hip_bfloat16* __restrict__ out,
    short* sBa, short* sBb)
{
    const int tid = threadIdx.x;
    const int lane = tid & 63;
    const int wid = tid >> 6;
    const int quad = lane >> 4;
    const int m16 = lane & 15;
    const float OC = 0.5f * 0.25f / 9.797958971132712f;
    const float SI1C = 0.17677669529663687f;

    // Ba: 20 frags f = ct*5+kt (ct 0..3, kt 0..4); K rows: [Wsi0 64 | W00 64 | W10 32]
    for (int i = tid; i < 20 * 512; i += 256) {
        int j = i & 7, ln = (i >> 3) & 63, f = i >> 9;
        int kt = f % 5, ct = f / 5;
        int k = kt * 32 + ((ln >> 4) << 3) + j;
        int col = ct * 16 + (ln & 15);
        short v;
        if (k < 64)       v = Wsi0[k * 64 + col];
        else if (k < 128) v = W00[(k - 64) * 64 + col];
        else              v = W10[(k - 128) * 64 + col];
        sBa[i] = v;
    }
    // Bb: 8 frags f = ct*4+kt (ct 0..1, kt 0..3); K rows: [Wsi1 32 | W01 64 | W11 32]
    for (int i = tid; i < 8 * 512; i += 256) {
        int j = i & 7, ln = (i >> 3) & 63, f = i >> 9;
        int kt = f & 3, ct = f >> 2;
        int k = kt * 32 + ((ln >> 4) << 3) + j;
        int col = ct * 16 + (ln & 15);
        short v;
        if (k < 32)      v = Wsi1[k * 32 + col];
        else if (k < 96) v = W01[(k - 32) * 32 + col];
        else             v = W11[(k - 96) * 32 + col];
        sBb[i] = v;
    }
    __syncthreads();

    int gw = blockIdx.x * 4 + wid;
    int nwv = gridDim.x * 4;
    for (int tile = gw; tile < OTILES; tile += nwv) {
        int tb = tile * 16;
        const short* nrow = ni + (size_t)(tb + m16) * 160;
        const short* srow = st + (size_t)(tb + m16) * 384;

        short8 af[5];
        af[0] = *(const short8*)(nrow + quad * 8);
        af[1] = *(const short8*)(nrow + 32 + quad * 8);
        af[2] = *(const short8*)(srow + quad * 8);
        af[3] = *(const short8*)(srow + 32 + quad * 8);
        af[4] = *(const short8*)(srow + 352 + quad * 8);

        float an[4];
#pragma unroll
        for (int r = 0; r < 4; ++r) an[r] = b2f(na[tb + quad * 4 + r]);

#pragma unroll
        for (int ct = 0; ct < 4; ++ct) {
            f32x4 aS = {0.f, 0.f, 0.f, 0.f};
            f32x4 aO = {0.f, 0.f, 0.f, 0.f};
            aS = __builtin_amdgcn_mfma_f32_16x16x32_bf16(
                af[0], *(const short8*)&sBa[(ct * 5 + 0) * 512 + lane * 8], aS, 0, 0, 0);
            aS = __builtin_amdgcn_mfma_f32_16x16x32_bf16(
                af[1], *(const short8*)&sBa[(ct * 5 + 1) * 512 + lane * 8], aS, 0, 0, 0);
            aO = __builtin_amdgcn_mfma_f32_16x16x32_bf16(
                af[2], *(const short8*)&sBa[(ct * 5 + 2) * 512 + lane * 8], aO, 0, 0, 0);
            aO = __builtin_amdgcn_mfma_f32_16x16x32_bf16(
                af[3], *(const short8*)&sBa[(ct * 5 + 3) * 512 + lane * 8], aO, 0, 0, 0);
            aO = __builtin_amdgcn_mfma_f32_16x16x32_bf16(
                af[4], *(const short8*)&sBa[(ct * 5 + 4) * 512 + lane * 8], aO, 0, 0, 0);
#pragma unroll
            for (int r = 0; r < 4; ++r)
                out[(size_t)(tb + quad * 4 + r) * 160 + ct * 16 + m16] =
                    __float2bfloat16(an[r] * (0.125f * aS[r] + OC * aO[r]));
        }

        short8 bb[8];
#pragma unroll
        for (int q = 0; q < 8; ++q)
            bb[q] = *(const short8*)&sBb[q * 512 + lane * 8];

#pragma unroll
        for (int d = 0; d < 3; ++d) {
            short8 ax;
#pragma unroll
            for (int j = 0; j < 8; ++j)
                ax[j] = nrow[64 + (quad * 8 + j) * 3 + d];
            short8 as1a = *(const short8*)(srow + 64 + d * 64 + quad * 8);
            short8 as1b = *(const short8*)(srow + 64 + d * 64 + 32 + quad * 8);
            short8 as2  = *(const short8*)(srow + 256 + d * 32 + quad * 8);
#pragma unroll
            for (int ct = 0; ct < 2; ++ct) {
                f32x4 aS = {0.f, 0.f, 0.f, 0.f};
                f32x4 aO = {0.f, 0.f, 0.f, 0.f};
                aS = __builtin_amdgcn_mfma_f32_16x16x32_bf16(ax,   bb[ct * 4 + 0], aS, 0, 0, 0);
                aO = __builtin_amdgcn_mfma_f32_16x16x32_bf16(as1a, bb[ct * 4 + 1], aO, 0, 0, 0);
                aO = __builtin_amdgcn_mfma_f32_16x16x32_bf16(as1b, bb[ct * 4 + 2], aO, 0, 0, 0);
                aO = __builtin_amdgcn_mfma_f32_16x16x32_bf16(as2,  bb[ct * 4 + 3], aO, 0, 0, 0);
#pragma unroll
                for (int r = 0; r < 4; ++r)
                    out[(size_t)(tb + quad * 4 + r) * 160 + 64 + (ct * 16 + m16) * 3 + d] =
                        __float2bfloat16(an[r] * (SI1C * aS[r] + OC * aO[r]));
            }
        }
    }
}

__global__ __launch_bounds__(256) void output_kernel(
    const void* node_input, const void* node_attr,
    const void* W_si0, const void* W_si1,
    const void* W_l2_00, const void* W_l2_10,
    const void* W_l2_01, const void* W_l2_11,
    const __hip_bfloat16* s_table, void* out)
{
    __shared__ __attribute__((aligned(16))) short sBa[20 * 512];  // 20 KB
    __shared__ __attribute__((aligned(16))) short sBb[8 * 512];   // 8 KB
    if (input_is_f32(node_attr))
        output_f32((const float*)node_input, (const float*)node_attr,
                   (const float*)W_si0, (const float*)W_si1,
                   (const float*)W_l2_00, (const float*)W_l2_10,
                   (const float*)W_l2_01, (const float*)W_l2_11,
                   s_table, (float*)out);
    else
        output_mfma((const short*)node_input, (const __hip_bfloat16*)node_attr,
                    (const short*)W_si0, (const short*)W_si1,
                    (const short*)W_l2_00, (const short*)W_l2_10,
                    (const short*)W_l2_01, (const short*)W_l2_11,
                    (const short*)s_table, (__hip_bfloat16*)out, sBa, sBb);
}

extern "C" void kernel_launch(void* const* d_in, const int* in_sizes, int n_in,
                              void* d_out, int out_size, void* d_ws, size_t ws_size,
                              hipStream_t stream)
{
    const void* node_input = d_in[0];
    const void* node_attr  = d_in[1];
    const void* edge_attr  = d_in[2];
    const void* el         = d_in[3];
    const void* W_si0  = d_in[4];
    const void* W_si1  = d_in[5];
    const void* W_l1_0 = d_in[6];
    const void* W_l1_1 = d_in[7];
    const void* W_l2_00 = d_in[8];
    const void* W_l2_10 = d_in[9];
    const void* W_l2_01 = d_in[10];
    const void* W_l2_11 = d_in[11];
    const void* W_fc1  = d_in[12];
    const void* W_fc2  = d_in[13];
    const int* edge_src = (const int*)d_in[14];
    const int* edge_dst = (const int*)d_in[15];

    // ws layout: s_table bf16 (38.4 MB) | sorted_idx (3.2 MB) | counts (0.2 MB)
    __hip_bfloat16* s_table = (__hip_bfloat16*)d_ws;
    int* sorted_idx = (int*)((char*)d_ws + (size_t)N_NODES * 384 * 2);
    int* counts     = (int*)((char*)sorted_idx + (size_t)N_EDGES * 4);
    void* l_table = d_out;   // N*160 elements, overwritten by output_kernel

    size_t ws_used = (size_t)N_NODES * 384 * 2 + (size_t)N_EDGES * 4 + (size_t)N_NODES * 4;
    hipMemsetAsync(d_ws, 0, ws_used, stream);

    hist_kernel<<<(N_EDGES + 255) / 256, 256, 0, stream>>>(edge_dst, counts);
    scan_kernel<<<1, 1024, 0, stream>>>(counts);
    scatter_kernel<<<(N_EDGES + 255) / 256, 256, 0, stream>>>(edge_dst, counts, sorted_idx);
    segsort_kernel<<<(N_NODES + 255) / 256, 256, 0, stream>>>(counts, sorted_idx);

    node_linear_kernel<<<NODE_GRID, 256, 0, stream>>>(
        node_input, node_attr, W_l1_0, W_l1_1, l_table);
    edge_kernel<<<EDGE_GRID, 256, 0, stream>>>(
        edge_attr, el, W_fc1, W_fc2, edge_src, edge_dst, sorted_idx,
        l_table, s_table, node_attr);
    output_kernel<<<NODE_GRID, 256, 0, stream>>>(
        node_input, node_attr, W_si0, W_si1, W_l2_00, W_l2_10, W_l2_01, W_l2_11,
        s_table, d_out);
}

// Round 9
// 808.021 us; speedup vs baseline: 1.5343x; 1.2467x over previous
//
#include <hip/hip_runtime.h>
#include <hip/hip_bf16.h>

#define N_NODES 50000
#define N_EDGES 800000
#define NBASIS 10
#define NRADIAL 100
#define WNUMEL 192
#define OTILES 3125           // 50000 / 16, exact (node tiles for MFMA kernels)
#define EDGE_GRID 500         // 500 blocks x 4 waves = 2000 wave-chunks
#define NWAVES 2000
#define CHUNK 400             // nominal edges per wave before snapping
#define NODE_GRID 512
#define HSTRIDE 136           // shorts per h-row (128 + 8 pad)
#define WSTRIDE 200           // shorts per w-row (192 + 8 pad)
#define WAVE_HW 3200          // shorts per wave region of sHW
// s_table: bf16, 384 per node, plane layout:
// [0:64]=s0 | [64:128]=s1x [128:192]=s1y [192:256]=s1z
// [256:288]=s2x [288:320]=s2y [320:352]=s2z | [352:384]=s3

typedef __attribute__((ext_vector_type(8))) short short8;
typedef __attribute__((ext_vector_type(4))) float f32x4;

__device__ __forceinline__ float b2f(__hip_bfloat16 x) { return __bfloat162float(x); }
__device__ __forceinline__ float ldv(const float* p, size_t i) { return p[i]; }
__device__ __forceinline__ float ldv(const __hip_bfloat16* p, size_t i) { return b2f(p[i]); }

__device__ __forceinline__ bool input_is_f32(const void* node_attr) {
    return ((const unsigned short*)node_attr)[0] == 0;   // bf16(1.0)=0x3F80
}

__device__ __forceinline__ short bfbits(float v) {
    __hip_bfloat16 h = __float2bfloat16(v);
    unsigned short u; __builtin_memcpy(&u, &h, 2);
    return (short)u;
}

// element -> bf16 bits (identity for bf16-as-short input, convert for f32)
__device__ __forceinline__ short ldbf(const short* p, size_t i) { return p[i]; }
__device__ __forceinline__ short ldbf(const float* p, size_t i) { return bfbits(p[i]); }

// 8 contiguous elements -> bf16 A-fragment
__device__ __forceinline__ short8 frag8(const short* p) { return *(const short8*)p; }
__device__ __forceinline__ short8 frag8(const float* p) {
    short8 r;
#pragma unroll
    for (int j = 0; j < 8; ++j) r[j] = bfbits(p[j]);
    return r;
}

// typed output store
__device__ __forceinline__ void stout(float* p, size_t i, float v) { p[i] = v; }
__device__ __forceinline__ void stout(__hip_bfloat16* p, size_t i, float v) { p[i] = __float2bfloat16(v); }

__device__ __forceinline__ unsigned int pack_bf2(float x, float y) {
    __hip_bfloat162 h;
    h.x = __float2bfloat16(x);
    h.y = __float2bfloat16(y);
    unsigned int u;
    __builtin_memcpy(&u, &h, 4);
    return u;
}

// __syncthreads() minus the vmcnt(0) drain.
__device__ __forceinline__ void sync_lds() {
    asm volatile("s_waitcnt lgkmcnt(0)" ::: "memory");
    __builtin_amdgcn_s_barrier();
}

// ---------------------------------------------------------------------------
// Sort kernels: counting sort of edges by dst + stabilizing segment sort +
// segment-snapped wave-chunk boundaries.
// ---------------------------------------------------------------------------
__global__ __launch_bounds__(256) void hist_kernel(const int* __restrict__ edge_dst,
                                                   int* __restrict__ counts) {
    int i = blockIdx.x * 256 + threadIdx.x;
    if (i < N_EDGES) atomicAdd(&counts[edge_dst[i]], 1);
}

__global__ __launch_bounds__(1024) void scan_kernel(int* __restrict__ counts) {
    __shared__ int lsum[1024];
    int t = threadIdx.x;
    int lo = t * 49;
    int hi = min(lo + 49, N_NODES);
    int s = 0;
    for (int i = lo; i < hi; ++i) s += counts[i];
    lsum[t] = s;
    __syncthreads();
    for (int off = 1; off < 1024; off <<= 1) {
        int add = (t >= off) ? lsum[t - off] : 0;
        __syncthreads();
        lsum[t] += add;
        __syncthreads();
    }
    int running = lsum[t] - s;   // exclusive prefix
    for (int i = lo; i < hi; ++i) { int c = counts[i]; counts[i] = running; running += c; }
}

__global__ __launch_bounds__(256) void scatter_kernel(const int* __restrict__ edge_dst,
                                                      int* __restrict__ counts,
                                                      int* __restrict__ sorted_idx) {
    int i = blockIdx.x * 256 + threadIdx.x;
    if (i < N_EDGES) {
        int p = atomicAdd(&counts[edge_dst[i]], 1);
        sorted_idx[p] = i;
    }
}

// Stable order within each dst segment -> deterministic edge order every run.
__global__ __launch_bounds__(256) void segsort_kernel(const int* __restrict__ counts,
                                                      int* __restrict__ sorted_idx) {
    int n = blockIdx.x * 256 + threadIdx.x;
    if (n >= N_NODES) return;
    int start = (n == 0) ? 0 : counts[n - 1];
    int end = counts[n];
    for (int i = start + 1; i < end; ++i) {
        int v = sorted_idx[i];
        int j = i - 1;
        while (j >= start && sorted_idx[j] > v) { sorted_idx[j + 1] = sorted_idx[j]; --j; }
        sorted_idx[j + 1] = v;
    }
}

// Snap wave-chunk starts forward to the next dst-segment boundary. Max degree
// (~50) << CHUNK, so chunks stay in [CHUNK-maxdeg, CHUNK+maxdeg] and are never
// empty. Result: no node's segment straddles two waves -> the edge kernel
// needs NO atomics on s_table (each node written once, by one wave) -> the
// whole pipeline is a deterministic pure function (the R7..R13 flaky-tripwire
// class is structurally gone).
__global__ __launch_bounds__(256) void snap_kernel(const int* __restrict__ sorted_idx,
                                                   const int* __restrict__ edge_dst,
                                                   int* __restrict__ wstart) {
    int w = blockIdx.x * 256 + threadIdx.x;
    if (w > NWAVES) return;
    if (w == 0)       { wstart[0] = 0; return; }
    if (w == NWAVES)  { wstart[NWAVES] = N_EDGES; return; }
    int pos = w * CHUNK;
    int prev = edge_dst[sorted_idx[pos - 1]];
    while (pos < N_EDGES && edge_dst[sorted_idx[pos]] == prev) ++pos;
    wstart[w] = pos;
}

// ---------------------------------------------------------------------------
// Kernel 1: per-node linear via MFMA (fragment layout HW-validated R9/R12).
// ---------------------------------------------------------------------------
template <class TI, class TA, class TO>
__device__ __forceinline__ void node_linear_mfma_t(
    const TI* __restrict__ ni, const TA* __restrict__ na,
    const TI* __restrict__ W0, const TI* __restrict__ W1,
    TO* __restrict__ lt, short* sB0, short* sB1)
{
    const int tid = threadIdx.x;
    const int lane = tid & 63;
    const int wid = tid >> 6;
    const int quad = lane >> 4;
    const int m16 = lane & 15;

    for (int i = tid; i < 8 * 512; i += 256) {
        int j = i & 7, ln = (i >> 3) & 63, f = i >> 9;
        int kt = f & 1, ct = f >> 1;
        int k = kt * 32 + ((ln >> 4) << 3) + j;
        int col = ct * 16 + (ln & 15);
        sB0[i] = ldbf(W0, (size_t)k * 64 + col);
    }
    for (int i = tid; i < 2 * 512; i += 256) {
        int j = i & 7, ln = (i >> 3) & 63, ct = i >> 9;
        int k = ((ln >> 4) << 3) + j;
        int col = ct * 16 + (ln & 15);
        sB1[i] = ldbf(W1, (size_t)k * 32 + col);
    }
    __syncthreads();

    int gw = blockIdx.x * 4 + wid;
    int nwv = gridDim.x * 4;
    for (int tile = gw; tile < OTILES; tile += nwv) {
        int tb = tile * 16;
        const TI* arow = ni + (size_t)(tb + m16) * 160;

        short8 a0[2];
        a0[0] = frag8(arow + quad * 8);
        a0[1] = frag8(arow + 32 + quad * 8);

        f32x4 acc0[4];
#pragma unroll
        for (int ct = 0; ct < 4; ++ct) {
            f32x4 acc = {0.f, 0.f, 0.f, 0.f};
            acc = __builtin_amdgcn_mfma_f32_16x16x32_bf16(
                a0[0], *(const short8*)&sB0[(ct * 2 + 0) * 512 + lane * 8], acc, 0, 0, 0);
            acc = __builtin_amdgcn_mfma_f32_16x16x32_bf16(
                a0[1], *(const short8*)&sB0[(ct * 2 + 1) * 512 + lane * 8], acc, 0, 0, 0);
            acc0[ct] = acc;
        }

        f32x4 acc1[3][2];
#pragma unroll
        for (int d = 0; d < 3; ++d) {
            short8 a1;
#pragma unroll
            for (int j = 0; j < 8; ++j)
                a1[j] = ldbf(arow, 64 + (quad * 8 + j) * 3 + d);
#pragma unroll
            for (int ct = 0; ct < 2; ++ct) {
                f32x4 acc = {0.f, 0.f, 0.f, 0.f};
                acc = __builtin_amdgcn_mfma_f32_16x16x32_bf16(
                    a1, *(const short8*)&sB1[ct * 512 + lane * 8], acc, 0, 0, 0);
                acc1[d][ct] = acc;
            }
        }

        float an[4];
#pragma unroll
        for (int r = 0; r < 4; ++r) an[r] = ldv(na, tb + quad * 4 + r);

#pragma unroll
        for (int ct = 0; ct < 4; ++ct)
#pragma unroll
            for (int r = 0; r < 4; ++r)
                stout(lt, (size_t)(tb + quad * 4 + r) * 160 + ct * 16 + m16,
                      acc0[ct][r] * an[r] * 0.125f);
#pragma unroll
        for (int d = 0; d < 3; ++d)
#pragma unroll
            for (int ct = 0; ct < 2; ++ct)
#pragma unroll
                for (int r = 0; r < 4; ++r)
                    stout(lt, (size_t)(tb + quad * 4 + r) * 160 + 64 + (ct * 16 + m16) * 3 + d,
                          acc1[d][ct][r] * an[r] * 0.17677669529663687f);
    }
}

__global__ __launch_bounds__(256) void node_linear_kernel(
    const void* node_input, const void* node_attr,
    const void* W_l1_0, const void* W_l1_1, void* l_table)
{
    __shared__ __attribute__((aligned(16))) short sB0[8 * 512];   // 8 KB
    __shared__ __attribute__((aligned(16))) short sB1[2 * 512];   // 2 KB
    if (input_is_f32(node_attr))
        node_linear_mfma_t<float, float, float>(
            (const float*)node_input, (const float*)node_attr,
            (const float*)W_l1_0, (const float*)W_l1_1, (float*)l_table, sB0, sB1);
    else
        node_linear_mfma_t<short, __hip_bfloat16, __hip_bfloat16>(
            (const short*)node_input, (const __hip_bfloat16*)node_attr,
            (const short*)W_l1_0, (const short*)W_l1_1,
            (__hip_bfloat16*)l_table, sB0, sB1);
}

// ---------------------------------------------------------------------------
// store: PLAIN (non-atomic) store of 8 accumulator components. Snapped chunks
// guarantee each node is written by exactly one wave, exactly once.
// ---------------------------------------------------------------------------
__device__ __forceinline__ void store_acc(
    __hip_bfloat16* __restrict__ s_table, int dst, int lane,
    float A0, float A1x, float A1y, float A1z,
    float A2x, float A2y, float A2z, float A3)
{
    if (dst < 0) return;
    __hip_bfloat16* srow = s_table + (size_t)dst * 384;
    float B0  = __shfl_down(A0, 1);
    float B1x = __shfl_down(A1x, 1);
    float B1y = __shfl_down(A1y, 1);
    float B1z = __shfl_down(A1z, 1);
    float B2x = __shfl_down(A2x, 1);
    float B2y = __shfl_down(A2y, 1);
    float B2z = __shfl_down(A2z, 1);
    float B3  = __shfl_down(A3, 1);
    if ((lane & 1) == 0) {
        *(unsigned int*)(srow + lane)       = pack_bf2(A0, B0);
        *(unsigned int*)(srow + 64 + lane)  = pack_bf2(A1x, B1x);
        *(unsigned int*)(srow + 128 + lane) = pack_bf2(A1y, B1y);
        *(unsigned int*)(srow + 192 + lane) = pack_bf2(A1z, B1z);
        if (lane < 32) {
            *(unsigned int*)(srow + 256 + lane) = pack_bf2(A2x, B2x);
            *(unsigned int*)(srow + 288 + lane) = pack_bf2(A2y, B2y);
            *(unsigned int*)(srow + 320 + lane) = pack_bf2(A2z, B2z);
            *(unsigned int*)(srow + 352 + lane) = pack_bf2(A3, B3);
        }
    }
}

// ---------------------------------------------------------------------------
// Kernel 2: edge kernel over snapped wave-chunks. Variable windows per wave:
// block runs max(nwin) windows; phases 0-2 clamp indices, phase 3 breaks on
// the wave-uniform validity bound. Run accumulator carried across windows;
// each node flushed once with a plain store.
// ---------------------------------------------------------------------------
template <class T>
__device__ __forceinline__ void edge_body(
    const T* __restrict__ edge_attr, const T* __restrict__ el,
    const T* __restrict__ W_fc1, const T* __restrict__ W_fc2,
    const int* __restrict__ edge_src, const int* __restrict__ edge_dst,
    const int* __restrict__ sorted_idx, const int* __restrict__ wstart,
    const T* __restrict__ l_table, __hip_bfloat16* __restrict__ s_table,
    __hip_bfloat16* sW1T, short* sW2B, short* sHW,
    int* sSrc, int* sDst, float* sAttr, int* sWs)
{
    __hip_bfloat16* sHWb = reinterpret_cast<__hip_bfloat16*>(sHW);
    const int tid = threadIdx.x;
    const int lane = tid & 63;
    const int wid = tid >> 6;
    const int quad = lane >> 4;
    const int m16 = lane & 15;
    const int wb16 = wid * 16;
    const int whw = wid * WAVE_HW;

    if (tid < 5) sWs[tid] = wstart[blockIdx.x * 4 + tid];
    for (int i = tid; i < NBASIS * NRADIAL; i += 256) {
        int k = i / NBASIS, b = i - k * NBASIS;
        sW1T[k * 16 + b] = __float2bfloat16(ldv(W_fc1, (size_t)b * NRADIAL + k));
    }
    for (int i = tid; i < 12 * 4 * 64 * 8; i += 256) {
        int j = i & 7, ln = (i >> 3) & 63, kt = (i >> 9) & 3, t = i >> 11;
        int k = kt * 32 + ((ln >> 4) * 8) + j;
        int n = t * 16 + (ln & 15);
        reinterpret_cast<__hip_bfloat16*>(sW2B)[i] =
            (k < NRADIAL) ? __float2bfloat16(ldv(W_fc2, (size_t)k * WNUMEL + n))
                          : __float2bfloat16(0.f);
    }
    __syncthreads();

    const int e0r = tid >> 2;       // row 0..63 (16 per wave)
    const int part = tid & 3;       // k-quarter of the row's MLP
    const int rwave = e0r >> 4;     // wave owning this row
    const int r16 = e0r & 15;
    const int hbase = rwave * WAVE_HW + r16 * HSTRIDE;

    const int ws_r = sWs[rwave];            // row's wave chunk bounds
    const int we_r = sWs[rwave + 1];
    const int ws_w = sWs[wid];              // own wave chunk bounds (phase 3)
    const int we_w = sWs[wid + 1];

    int nwinB = 0;                           // block-uniform window count
#pragma unroll
    for (int i = 0; i < 4; ++i) {
        int nw = (sWs[i + 1] - sWs[i] + 15) >> 4;
        nwinB = max(nwinB, nw);
    }

    // ---- prologue: prefetch window 0 (always fully valid; chunk >= 350)
    int eg = sorted_idx[ws_r + r16];
    float elv[NBASIS];
#pragma unroll
    for (int b = 0; b < NBASIS; ++b) elv[b] = ldv(el, (size_t)eg * NBASIS + b);
    int mi = 0; float ma = 0.f, mb = 0.f;
    if (part == 0)      mi = edge_src[eg];
    else if (part == 1) mi = edge_dst[eg];
    else if (part == 2) { ma = ldv(edge_attr, (size_t)eg * 4 + 0); mb = ldv(edge_attr, (size_t)eg * 4 + 1); }
    else                { ma = ldv(edge_attr, (size_t)eg * 4 + 2); mb = ldv(edge_attr, (size_t)eg * 4 + 3); }

    float A0 = 0.f, A1x = 0.f, A1y = 0.f, A1z = 0.f;
    float A2x = 0.f, A2y = 0.f, A2z = 0.f, A3 = 0.f;
    int cur_dst = -1;

    for (int it = 0; it < nwinB; ++it) {
        // ---- metadata stage (registers -> LDS); clamped duplicates are
        // written for invalid rows but never read (phase 3 breaks first)
        if (part == 0)      sSrc[e0r] = mi;
        else if (part == 1) sDst[e0r] = mi;
        else if (part == 2) { sAttr[e0r * 4 + 0] = ma; sAttr[e0r * 4 + 1] = mb; }
        else                { sAttr[e0r * 4 + 2] = ma; sAttr[e0r * 4 + 3] = mb; }

        // ---- phase 0: layer-1 MLP from register elv
        {
            const float HS = 0.04472135954999579f;
            for (int kk = 0; kk < 25; ++kk) {
                int k = part * 25 + kk;
                const unsigned int* wp = (const unsigned int*)&sW1T[k * 16];
                float z = 0.f;
#pragma unroll
                for (int b2 = 0; b2 < 5; ++b2) {
                    unsigned int w2 = wp[b2];
                    __hip_bfloat162 hw;
                    __builtin_memcpy(&hw, &w2, 4);
                    z += elv[2 * b2] * b2f(hw.x) + elv[2 * b2 + 1] * b2f(hw.y);
                }
                sHWb[hbase + k] = __float2bfloat16(fmaxf(z, 0.f) * HS);
            }
            for (int k = 100 + part * 7; k < 107 + part * 7; ++k)
                sHWb[hbase + k] = __float2bfloat16(0.f);
        }

        // ---- issue next window's sorted_idx load (clamped to chunk end)
        int np = ws_r + (it + 1) * 16 + r16;
        int npc = (np < we_r) ? np : (we_r - 1);
        int next_eg = sorted_idx[npc];

        sync_lds();

        // ---- phase 1: A-fragment loads (wave's 16 edges)
        short8 afrag[4];
#pragma unroll
        for (int kt = 0; kt < 4; ++kt)
            afrag[kt] = *(const short8*)&sHW[whw + m16 * HSTRIDE + kt * 32 + quad * 8];

        // ---- phase-3 gather prefetch: 16-deep l_table reads fly during GEMM
        int srcs[16];
#pragma unroll
        for (int i = 0; i < 16; ++i) srcs[i] = sSrc[wb16 + i];
        float y0p[16];
        float y1p[16][3];
#pragma unroll
        for (int i = 0; i < 16; ++i)
            y0p[i] = ldv(l_table + (size_t)srcs[i] * 160, lane);
        if (lane < 32) {
#pragma unroll
            for (int i = 0; i < 16; ++i) {
                const T* lrow = l_table + (size_t)srcs[i] * 160 + 64 + lane * 3;
                y1p[i][0] = ldv(lrow, 0);
                y1p[i][1] = ldv(lrow, 1);
                y1p[i][2] = ldv(lrow, 2);
            }
        }

        // ---- phase 2: GEMM w = h @ W2 into this wave's sHW rows
#pragma unroll
        for (int t = 0; t < 12; ++t) {
            f32x4 acc = {0.f, 0.f, 0.f, 0.f};
#pragma unroll
            for (int kt = 0; kt < 4; ++kt) {
                short8 bfrag = *(const short8*)&sW2B[(((t * 4) + kt) * 64 + lane) * 8];
                acc = __builtin_amdgcn_mfma_f32_16x16x32_bf16(afrag[kt], bfrag, acc, 0, 0, 0);
            }
#pragma unroll
            for (int r = 0; r < 4; ++r)
                sHWb[whw + (quad * 4 + r) * WSTRIDE + t * 16 + m16] = __float2bfloat16(acc[r]);
        }

        // ---- issue next window's elv / metadata loads (hidden under phase 3)
        float elvN[NBASIS]; int miN = 0; float maN = 0.f, mbN = 0.f;
#pragma unroll
        for (int b = 0; b < NBASIS; ++b) elvN[b] = ldv(el, (size_t)next_eg * NBASIS + b);
        if (part == 0)      miN = edge_src[next_eg];
        else if (part == 1) miN = edge_dst[next_eg];
        else if (part == 2) { maN = ldv(edge_attr, (size_t)next_eg * 4 + 0); mbN = ldv(edge_attr, (size_t)next_eg * 4 + 1); }
        else                { maN = ldv(edge_attr, (size_t)next_eg * 4 + 2); mbN = ldv(edge_attr, (size_t)next_eg * 4 + 3); }

        sync_lds();

        // ---- phase 3: run-aggregated messages; wave-uniform validity break
        int nval = we_w - (ws_w + it * 16);   // edges valid in this window
#pragma unroll
        for (int i = 0; i < 16; ++i) {
            if (i >= nval) break;
            int elc = wb16 + i;
            int dst = sDst[elc];
            if (dst != cur_dst) {
                store_acc(s_table, cur_dst, lane, A0, A1x, A1y, A1z, A2x, A2y, A2z, A3);
                A0 = A1x = A1y = A1z = A2x = A2y = A2z = A3 = 0.f;
                cur_dst = dst;
            }
            float e0  = sAttr[elc * 4 + 0];
            float e1x = sAttr[elc * 4 + 1];
            float e1y = sAttr[elc * 4 + 2];
            float e1z = sAttr[elc * 4 + 3];

            int wrow = whw + i * WSTRIDE;
            float y0 = y0p[i];
            float w_a = b2f(sHWb[wrow + lane]);
            float w_b = b2f(sHWb[wrow + 64 + lane]);

            A0 += w_a * y0 * e0;
            float m1b = w_b * y0;
            A1x += m1b * e1x; A1y += m1b * e1y; A1z += m1b * e1z;
            if (lane < 32) {
                float w_c = b2f(sHWb[wrow + 128 + lane]);
                float w3v = b2f(sHWb[wrow + 160 + lane]);
                float g = w_c * e0;
                A2x += g * y1p[i][0]; A2y += g * y1p[i][1]; A2z += g * y1p[i][2];
                float dot = y1p[i][0] * e1x + y1p[i][1] * e1y + y1p[i][2] * e1z;
                A3 += w3v * dot * 0.5773502691896258f;
            }
        }

        eg = next_eg;
#pragma unroll
        for (int b = 0; b < NBASIS; ++b) elv[b] = elvN[b];
        mi = miN; ma = maN; mb = mbN;

        sync_lds();
    }
    // final store of the carried run (each node exclusively owned: plain store)
    store_acc(s_table, cur_dst, lane, A0, A1x, A1y, A1z, A2x, A2y, A2z, A3);
}

__global__ __launch_bounds__(256) void edge_kernel(
    const void* edge_attr, const void* el, const void* W_fc1, const void* W_fc2,
    const int* edge_src, const int* edge_dst, const int* sorted_idx,
    const int* wstart, const void* l_table, __hip_bfloat16* s_table,
    const void* node_attr)
{
    __shared__ __hip_bfloat16 sW1T[NRADIAL * 16];
    __shared__ short sW2B[12 * 4 * 64 * 8];
    __shared__ short sHW[64 * WSTRIDE];
    __shared__ int sSrc[64], sDst[64];
    __shared__ float sAttr[256];
    __shared__ int sWs[5];
    if (input_is_f32(node_attr))
        edge_body<float>((const float*)edge_attr, (const float*)el,
                         (const float*)W_fc1, (const float*)W_fc2,
                         edge_src, edge_dst, sorted_idx, wstart,
                         (const float*)l_table, s_table,
                         sW1T, sW2B, sHW, sSrc, sDst, sAttr, sWs);
    else
        edge_body<__hip_bfloat16>((const __hip_bfloat16*)edge_attr,
                                  (const __hip_bfloat16*)el,
                                  (const __hip_bfloat16*)W_fc1,
                                  (const __hip_bfloat16*)W_fc2,
                                  edge_src, edge_dst, sorted_idx, wstart,
                                  (const __hip_bfloat16*)l_table, s_table,
                                  sW1T, sW2B, sHW, sSrc, sDst, sAttr, sWs);
}

// ---------------------------------------------------------------------------
// Kernel 3: output via MFMA (layout HW-validated); templated input type.
// ---------------------------------------------------------------------------
template <class TI, class TA, class TO>
__device__ __forceinline__ void output_mfma_t(
    const TI* __restrict__ ni, const TA* __restrict__ na,
    const TI* __restrict__ Wsi0, const TI* __restrict__ Wsi1,
    const TI* __restrict__ W00, const TI* __restrict__ W10,
    const TI* __restrict__ W01, const TI* __restrict__ W11,
    const short* __restrict__ st, TO* __restrict__ out,
    short* sBa, short* sBb)
{
    const int tid = threadIdx.x;
    const int lane = tid & 63;
    const int wid = tid >> 6;
    const int quad = lane >> 4;
    const int m16 = lane & 15;
    const float OC = 0.5f * 0.25f / 9.797958971132712f;
    const float SI1C = 0.17677669529663687f;

    // Ba: 20 frags f = ct*5+kt (ct 0..3, kt 0..4); K rows: [Wsi0 64 | W00 64 | W10 32]
    for (int i = tid; i < 20 * 512; i += 256) {
        int j = i & 7, ln = (i >> 3) & 63, f = i >> 9;
        int kt = f % 5, ct = f / 5;
        int k = kt * 32 + ((ln >> 4) << 3) + j;
        int col = ct * 16 + (ln & 15);
        short v;
        if (k < 64)       v = ldbf(Wsi0, (size_t)k * 64 + col);
        else if (k < 128) v = ldbf(W00, (size_t)(k - 64) * 64 + col);
        else              v = ldbf(W10, (size_t)(k - 128) * 64 + col);
        sBa[i] = v;
    }
    // Bb: 8 frags f = ct*4+kt (ct 0..1, kt 0..3); K rows: [Wsi1 32 | W01 64 | W11 32]
    for (int i = tid; i < 8 * 512; i += 256) {
        int j = i & 7, ln = (i >> 3) & 63, f = i >> 9;
        int kt = f & 3, ct = f >> 2;
        int k = kt * 32 + ((ln >> 4) << 3) + j;
        int col = ct * 16 + (ln & 15);
        short v;
        if (k < 32)      v = ldbf(Wsi1, (size_t)k * 32 + col);
        else if (k < 96) v = ldbf(W01, (size_t)(k - 32) * 32 + col);
        else             v = ldbf(W11, (size_t)(k - 96) * 32 + col);
        sBb[i] = v;
    }
    __syncthreads();

    int gw = blockIdx.x * 4 + wid;
    int nwv = gridDim.x * 4;
    for (int tile = gw; tile < OTILES; tile += nwv) {
        int tb = tile * 16;
        const TI* nrow = ni + (size_t)(tb + m16) * 160;
        const short* srow = st + (size_t)(tb + m16) * 384;

        short8 af[5];
        af[0] = frag8(nrow + quad * 8);
        af[1] = frag8(nrow + 32 + quad * 8);
        af[2] = *(const short8*)(srow + quad * 8);
        af[3] = *(const short8*)(srow + 32 + quad * 8);
        af[4] = *(const short8*)(srow + 352 + quad * 8);

        float an[4];
#pragma unroll
        for (int r = 0; r < 4; ++r) an[r] = ldv(na, tb + quad * 4 + r);

#pragma unroll
        for (int ct = 0; ct < 4; ++ct) {
            f32x4 aS = {0.f, 0.f, 0.f, 0.f};
            f32x4 aO = {0.f, 0.f, 0.f, 0.f};
            aS = __builtin_amdgcn_mfma_f32_16x16x32_bf16(
                af[0], *(const short8*)&sBa[(ct * 5 + 0) * 512 + lane * 8], aS, 0, 0, 0);
            aS = __builtin_amdgcn_mfma_f32_16x16x32_bf16(
                af[1], *(const short8*)&sBa[(ct * 5 + 1) * 512 + lane * 8], aS, 0, 0, 0);
            aO = __builtin_amdgcn_mfma_f32_16x16x32_bf16(
                af[2], *(const short8*)&sBa[(ct * 5 + 2) * 512 + lane * 8], aO, 0, 0, 0);
            aO = __builtin_amdgcn_mfma_f32_16x16x32_bf16(
                af[3], *(const short8*)&sBa[(ct * 5 + 3) * 512 + lane * 8], aO, 0, 0, 0);
            aO = __builtin_amdgcn_mfma_f32_16x16x32_bf16(
                af[4], *(const short8*)&sBa[(ct * 5 + 4) * 512 + lane * 8], aO, 0, 0, 0);
#pragma unroll
            for (int r = 0; r < 4; ++r)
                stout(out, (size_t)(tb + quad * 4 + r) * 160 + ct * 16 + m16,
                      an[r] * (0.125f * aS[r] + OC * aO[r]));
        }

        short8 bb[8];
#pragma unroll
        for (int q = 0; q < 8; ++q)
            bb[q] = *(const short8*)&sBb[q * 512 + lane * 8];

#pragma unroll
        for (int d = 0; d < 3; ++d) {
            short8 ax;
#pragma unroll
            for (int j = 0; j < 8; ++j)
                ax[j] = ldbf(nrow, 64 + (quad * 8 + j) * 3 + d);
            short8 as1a = *(const short8*)(srow + 64 + d * 64 + quad * 8);
            short8 as1b = *(const short8*)(srow + 64 + d * 64 + 32 + quad * 8);
            short8 as2  = *(const short8*)(srow + 256 + d * 32 + quad * 8);
#pragma unroll
            for (int ct = 0; ct < 2; ++ct) {
                f32x4 aS = {0.f, 0.f, 0.f, 0.f};
                f32x4 aO = {0.f, 0.f, 0.f, 0.f};
                aS = __builtin_amdgcn_mfma_f32_16x16x32_bf16(ax,   bb[ct * 4 + 0], aS, 0, 0, 0);
                aO = __builtin_amdgcn_mfma_f32_16x16x32_bf16(as1a, bb[ct * 4 + 1], aO, 0, 0, 0);
                aO = __builtin_amdgcn_mfma_f32_16x16x32_bf16(as1b, bb[ct * 4 + 2], aO, 0, 0, 0);
                aO = __builtin_amdgcn_mfma_f32_16x16x32_bf16(as2,  bb[ct * 4 + 3], aO, 0, 0, 0);
#pragma unroll
                for (int r = 0; r < 4; ++r)
                    stout(out, (size_t)(tb + quad * 4 + r) * 160 + 64 + (ct * 16 + m16) * 3 + d,
                          an[r] * (SI1C * aS[r] + OC * aO[r]));
            }
        }
    }
}

__global__ __launch_bounds__(256) void output_kernel(
    const void* node_input, const void* node_attr,
    const void* W_si0, const void* W_si1,
    const void* W_l2_00, const void* W_l2_10,
    const void* W_l2_01, const void* W_l2_11,
    const __hip_bfloat16* s_table, void* out)
{
    __shared__ __attribute__((aligned(16))) short sBa[20 * 512];  // 20 KB
    __shared__ __attribute__((aligned(16))) short sBb[8 * 512];   // 8 KB
    if (input_is_f32(node_attr))
        output_mfma_t<float, float, float>(
            (const float*)node_input, (const float*)node_attr,
            (const float*)W_si0, (const float*)W_si1,
            (const float*)W_l2_00, (const float*)W_l2_10,
            (const float*)W_l2_01, (const float*)W_l2_11,
            (const short*)s_table, (float*)out, sBa, sBb);
    else
        output_mfma_t<short, __hip_bfloat16, __hip_bfloat16>(
            (const short*)node_input, (const __hip_bfloat16*)node_attr,
            (const short*)W_si0, (const short*)W_si1,
            (const short*)W_l2_00, (const short*)W_l2_10,
            (const short*)W_l2_01, (const short*)W_l2_11,
            (const short*)s_table, (__hip_bfloat16*)out, sBa, sBb);
}

extern "C" void kernel_launch(void* const* d_in, const int* in_sizes, int n_in,
                              void* d_out, int out_size, void* d_ws, size_t ws_size,
                              hipStream_t stream)
{
    const void* node_input = d_in[0];
    const void* node_attr  = d_in[1];
    const void* edge_attr  = d_in[2];
    const void* el         = d_in[3];
    const void* W_si0  = d_in[4];
    const void* W_si1  = d_in[5];
    const void* W_l1_0 = d_in[6];
    const void* W_l1_1 = d_in[7];
    const void* W_l2_00 = d_in[8];
    const void* W_l2_10 = d_in[9];
    const void* W_l2_01 = d_in[10];
    const void* W_l2_11 = d_in[11];
    const void* W_fc1  = d_in[12];
    const void* W_fc2  = d_in[13];
    const int* edge_src = (const int*)d_in[14];
    const int* edge_dst = (const int*)d_in[15];

    // ws layout: s_table bf16 (38.4 MB) | sorted_idx (3.2 MB) | counts (0.2 MB)
    //            | wstart (2001 ints)
    __hip_bfloat16* s_table = (__hip_bfloat16*)d_ws;
    int* sorted_idx = (int*)((char*)d_ws + (size_t)N_NODES * 384 * 2);
    int* counts     = (int*)((char*)sorted_idx + (size_t)N_EDGES * 4);
    int* wstart     = counts + N_NODES;
    void* l_table = d_out;   // N*160 elements, overwritten by output_kernel

    size_t ws_used = (size_t)N_NODES * 384 * 2 + (size_t)N_EDGES * 4
                   + (size_t)N_NODES * 4 + (size_t)(NWAVES + 1) * 4;
    hipMemsetAsync(d_ws, 0, ws_used, stream);

    hist_kernel<<<(N_EDGES + 255) / 256, 256, 0, stream>>>(edge_dst, counts);
    scan_kernel<<<1, 1024, 0, stream>>>(counts);
    scatter_kernel<<<(N_EDGES + 255) / 256, 256, 0, stream>>>(edge_dst, counts, sorted_idx);
    segsort_kernel<<<(N_NODES + 255) / 256, 256, 0, stream>>>(counts, sorted_idx);
    snap_kernel<<<(NWAVES + 256) / 256, 256, 0, stream>>>(sorted_idx, edge_dst, wstart);

    node_linear_kernel<<<NODE_GRID, 256, 0, stream>>>(
        node_input, node_attr, W_l1_0, W_l1_1, l_table);
    edge_kernel<<<EDGE_GRID, 256, 0, stream>>>(
        edge_attr, el, W_fc1, W_fc2, edge_src, edge_dst, sorted_idx, wstart,
        l_table, s_table, node_attr);
    output_kernel<<<NODE_GRID, 256, 0, stream>>>(
        node_input, node_attr, W_si0, W_si1, W_l2_00, W_l2_10, W_l2_01, W_l2_11,
        s_table, d_out);
}

// Round 10
// 804.860 us; speedup vs baseline: 1.5404x; 1.0039x over previous
//
#include <hip/hip_runtime.h>
#include <hip/hip_bf16.h>

#define N_NODES 50000
#define N_EDGES 800000
#define NBASIS 10
#define NRADIAL 100
#define WNUMEL 192
#define OTILES 3125           // 50000 / 16, exact (node tiles for MFMA kernels)
#define EDGE_GRID 500         // 500 blocks x 4 waves = 2000 wave-chunks
#define NWAVES 2000
#define CHUNK 400             // nominal edges per wave before snapping
#define NODE_GRID 512
#define HSTRIDE 136           // shorts per h-row (128 + 8 pad)
#define WSTRIDE 200           // shorts per w-row (192 + 8 pad)
#define WAVE_HW 3200          // shorts per wave region of sHW
// s_table: bf16, 384 per node, plane layout:
// [0:64]=s0 | [64:128]=s1x [128:192]=s1y [192:256]=s1z
// [256:288]=s2x [288:320]=s2y [320:352]=s2z | [352:384]=s3
// l_table: bf16 in BOTH configs (halves the edge-kernel gather traffic;
// the f32 config tolerates the bf16 rounding: bf16-config margin proves it).

typedef __attribute__((ext_vector_type(8))) short short8;
typedef __attribute__((ext_vector_type(4))) float f32x4;

__device__ __forceinline__ float b2f(__hip_bfloat16 x) { return __bfloat162float(x); }
__device__ __forceinline__ float ldv(const float* p, size_t i) { return p[i]; }
__device__ __forceinline__ float ldv(const __hip_bfloat16* p, size_t i) { return b2f(p[i]); }

__device__ __forceinline__ bool input_is_f32(const void* node_attr) {
    return ((const unsigned short*)node_attr)[0] == 0;   // bf16(1.0)=0x3F80
}

__device__ __forceinline__ short bfbits(float v) {
    __hip_bfloat16 h = __float2bfloat16(v);
    unsigned short u; __builtin_memcpy(&u, &h, 2);
    return (short)u;
}

// element -> bf16 bits (identity for bf16-as-short input, convert for f32)
__device__ __forceinline__ short ldbf(const short* p, size_t i) { return p[i]; }
__device__ __forceinline__ short ldbf(const float* p, size_t i) { return bfbits(p[i]); }

// 8 contiguous elements -> bf16 A-fragment
__device__ __forceinline__ short8 frag8(const short* p) { return *(const short8*)p; }
__device__ __forceinline__ short8 frag8(const float* p) {
    short8 r;
#pragma unroll
    for (int j = 0; j < 8; ++j) r[j] = bfbits(p[j]);
    return r;
}

// typed output store
__device__ __forceinline__ void stout(float* p, size_t i, float v) { p[i] = v; }
__device__ __forceinline__ void stout(__hip_bfloat16* p, size_t i, float v) { p[i] = __float2bfloat16(v); }

__device__ __forceinline__ unsigned int pack_bf2(float x, float y) {
    __hip_bfloat162 h;
    h.x = __float2bfloat16(x);
    h.y = __float2bfloat16(y);
    unsigned int u;
    __builtin_memcpy(&u, &h, 4);
    return u;
}

// __syncthreads() minus the vmcnt(0) drain.
__device__ __forceinline__ void sync_lds() {
    asm volatile("s_waitcnt lgkmcnt(0)" ::: "memory");
    __builtin_amdgcn_s_barrier();
}

// ---------------------------------------------------------------------------
// Sort kernels: counting sort of edges by dst + stabilizing segment sort +
// segment-snapped wave-chunk boundaries.
// ---------------------------------------------------------------------------
__global__ __launch_bounds__(256) void hist_kernel(const int* __restrict__ edge_dst,
                                                   int* __restrict__ counts) {
    int i = blockIdx.x * 256 + threadIdx.x;
    if (i < N_EDGES) atomicAdd(&counts[edge_dst[i]], 1);
}

__global__ __launch_bounds__(1024) void scan_kernel(int* __restrict__ counts) {
    __shared__ int lsum[1024];
    int t = threadIdx.x;
    int lo = t * 49;
    int hi = min(lo + 49, N_NODES);
    int s = 0;
    for (int i = lo; i < hi; ++i) s += counts[i];
    lsum[t] = s;
    __syncthreads();
    for (int off = 1; off < 1024; off <<= 1) {
        int add = (t >= off) ? lsum[t - off] : 0;
        __syncthreads();
        lsum[t] += add;
        __syncthreads();
    }
    int running = lsum[t] - s;   // exclusive prefix
    for (int i = lo; i < hi; ++i) { int c = counts[i]; counts[i] = running; running += c; }
}

__global__ __launch_bounds__(256) void scatter_kernel(const int* __restrict__ edge_dst,
                                                      int* __restrict__ counts,
                                                      int* __restrict__ sorted_idx) {
    int i = blockIdx.x * 256 + threadIdx.x;
    if (i < N_EDGES) {
        int p = atomicAdd(&counts[edge_dst[i]], 1);
        sorted_idx[p] = i;
    }
}

// Stable order within each dst segment -> deterministic edge order every run.
__global__ __launch_bounds__(256) void segsort_kernel(const int* __restrict__ counts,
                                                      int* __restrict__ sorted_idx) {
    int n = blockIdx.x * 256 + threadIdx.x;
    if (n >= N_NODES) return;
    int start = (n == 0) ? 0 : counts[n - 1];
    int end = counts[n];
    for (int i = start + 1; i < end; ++i) {
        int v = sorted_idx[i];
        int j = i - 1;
        while (j >= start && sorted_idx[j] > v) { sorted_idx[j + 1] = sorted_idx[j]; --j; }
        sorted_idx[j + 1] = v;
    }
}

// Snap wave-chunk starts forward to the next dst-segment boundary -> no node
// straddles two waves -> plain stores, fully deterministic (validated R14).
__global__ __launch_bounds__(256) void snap_kernel(const int* __restrict__ sorted_idx,
                                                   const int* __restrict__ edge_dst,
                                                   int* __restrict__ wstart) {
    int w = blockIdx.x * 256 + threadIdx.x;
    if (w > NWAVES) return;
    if (w == 0)       { wstart[0] = 0; return; }
    if (w == NWAVES)  { wstart[NWAVES] = N_EDGES; return; }
    int pos = w * CHUNK;
    int prev = edge_dst[sorted_idx[pos - 1]];
    while (pos < N_EDGES && edge_dst[sorted_idx[pos]] == prev) ++pos;
    wstart[w] = pos;
}

// ---------------------------------------------------------------------------
// Kernel 1: per-node linear via MFMA (fragment layout HW-validated R9/R12).
// l_table output is ALWAYS bf16.
// ---------------------------------------------------------------------------
template <class TI, class TA>
__device__ __forceinline__ void node_linear_mfma_t(
    const TI* __restrict__ ni, const TA* __restrict__ na,
    const TI* __restrict__ W0, const TI* __restrict__ W1,
    __hip_bfloat16* __restrict__ lt, short* sB0, short* sB1)
{
    const int tid = threadIdx.x;
    const int lane = tid & 63;
    const int wid = tid >> 6;
    const int quad = lane >> 4;
    const int m16 = lane & 15;

    for (int i = tid; i < 8 * 512; i += 256) {
        int j = i & 7, ln = (i >> 3) & 63, f = i >> 9;
        int kt = f & 1, ct = f >> 1;
        int k = kt * 32 + ((ln >> 4) << 3) + j;
        int col = ct * 16 + (ln & 15);
        sB0[i] = ldbf(W0, (size_t)k * 64 + col);
    }
    for (int i = tid; i < 2 * 512; i += 256) {
        int j = i & 7, ln = (i >> 3) & 63, ct = i >> 9;
        int k = ((ln >> 4) << 3) + j;
        int col = ct * 16 + (ln & 15);
        sB1[i] = ldbf(W1, (size_t)k * 32 + col);
    }
    __syncthreads();

    int gw = blockIdx.x * 4 + wid;
    int nwv = gridDim.x * 4;
    for (int tile = gw; tile < OTILES; tile += nwv) {
        int tb = tile * 16;
        const TI* arow = ni + (size_t)(tb + m16) * 160;

        short8 a0[2];
        a0[0] = frag8(arow + quad * 8);
        a0[1] = frag8(arow + 32 + quad * 8);

        f32x4 acc0[4];
#pragma unroll
        for (int ct = 0; ct < 4; ++ct) {
            f32x4 acc = {0.f, 0.f, 0.f, 0.f};
            acc = __builtin_amdgcn_mfma_f32_16x16x32_bf16(
                a0[0], *(const short8*)&sB0[(ct * 2 + 0) * 512 + lane * 8], acc, 0, 0, 0);
            acc = __builtin_amdgcn_mfma_f32_16x16x32_bf16(
                a0[1], *(const short8*)&sB0[(ct * 2 + 1) * 512 + lane * 8], acc, 0, 0, 0);
            acc0[ct] = acc;
        }

        f32x4 acc1[3][2];
#pragma unroll
        for (int d = 0; d < 3; ++d) {
            short8 a1;
#pragma unroll
            for (int j = 0; j < 8; ++j)
                a1[j] = ldbf(arow, 64 + (quad * 8 + j) * 3 + d);
#pragma unroll
            for (int ct = 0; ct < 2; ++ct) {
                f32x4 acc = {0.f, 0.f, 0.f, 0.f};
                acc = __builtin_amdgcn_mfma_f32_16x16x32_bf16(
                    a1, *(const short8*)&sB1[ct * 512 + lane * 8], acc, 0, 0, 0);
                acc1[d][ct] = acc;
            }
        }

        float an[4];
#pragma unroll
        for (int r = 0; r < 4; ++r) an[r] = ldv(na, tb + quad * 4 + r);

#pragma unroll
        for (int ct = 0; ct < 4; ++ct)
#pragma unroll
            for (int r = 0; r < 4; ++r)
                lt[(size_t)(tb + quad * 4 + r) * 160 + ct * 16 + m16] =
                    __float2bfloat16(acc0[ct][r] * an[r] * 0.125f);
#pragma unroll
        for (int d = 0; d < 3; ++d)
#pragma unroll
            for (int ct = 0; ct < 2; ++ct)
#pragma unroll
                for (int r = 0; r < 4; ++r)
                    lt[(size_t)(tb + quad * 4 + r) * 160 + 64 + (ct * 16 + m16) * 3 + d] =
                        __float2bfloat16(acc1[d][ct][r] * an[r] * 0.17677669529663687f);
    }
}

__global__ __launch_bounds__(256) void node_linear_kernel(
    const void* node_input, const void* node_attr,
    const void* W_l1_0, const void* W_l1_1, void* l_table)
{
    __shared__ __attribute__((aligned(16))) short sB0[8 * 512];   // 8 KB
    __shared__ __attribute__((aligned(16))) short sB1[2 * 512];   // 2 KB
    if (input_is_f32(node_attr))
        node_linear_mfma_t<float, float>(
            (const float*)node_input, (const float*)node_attr,
            (const float*)W_l1_0, (const float*)W_l1_1,
            (__hip_bfloat16*)l_table, sB0, sB1);
    else
        node_linear_mfma_t<short, __hip_bfloat16>(
            (const short*)node_input, (const __hip_bfloat16*)node_attr,
            (const short*)W_l1_0, (const short*)W_l1_1,
            (__hip_bfloat16*)l_table, sB0, sB1);
}

// ---------------------------------------------------------------------------
// store: PLAIN (non-atomic) store of 8 accumulator components. Snapped chunks
// guarantee each node is written by exactly one wave, exactly once.
// ---------------------------------------------------------------------------
__device__ __forceinline__ void store_acc(
    __hip_bfloat16* __restrict__ s_table, int dst, int lane,
    float A0, float A1x, float A1y, float A1z,
    float A2x, float A2y, float A2z, float A3)
{
    if (dst < 0) return;
    __hip_bfloat16* srow = s_table + (size_t)dst * 384;
    float B0  = __shfl_down(A0, 1);
    float B1x = __shfl_down(A1x, 1);
    float B1y = __shfl_down(A1y, 1);
    float B1z = __shfl_down(A1z, 1);
    float B2x = __shfl_down(A2x, 1);
    float B2y = __shfl_down(A2y, 1);
    float B2z = __shfl_down(A2z, 1);
    float B3  = __shfl_down(A3, 1);
    if ((lane & 1) == 0) {
        *(unsigned int*)(srow + lane)       = pack_bf2(A0, B0);
        *(unsigned int*)(srow + 64 + lane)  = pack_bf2(A1x, B1x);
        *(unsigned int*)(srow + 128 + lane) = pack_bf2(A1y, B1y);
        *(unsigned int*)(srow + 192 + lane) = pack_bf2(A1z, B1z);
        if (lane < 32) {
            *(unsigned int*)(srow + 256 + lane) = pack_bf2(A2x, B2x);
            *(unsigned int*)(srow + 288 + lane) = pack_bf2(A2y, B2y);
            *(unsigned int*)(srow + 320 + lane) = pack_bf2(A2z, B2z);
            *(unsigned int*)(srow + 352 + lane) = pack_bf2(A3, B3);
        }
    }
}

// ---------------------------------------------------------------------------
// Kernel 2: edge kernel over snapped wave-chunks (R14 structure).
// R15: __launch_bounds__(256,2) — LDS already caps occupancy at 2 blocks/CU
// (8 waves/CU = 2/SIMD), so give the register allocator the full 256-VGPR
// budget; the 16-deep y0p/y1p gather prefetch then lives in registers instead
// of scratch (R14: VGPR=88 + ~270 MB of spill write traffic). l_table is bf16.
// ---------------------------------------------------------------------------
template <class T>
__device__ __forceinline__ void edge_body(
    const T* __restrict__ edge_attr, const T* __restrict__ el,
    const T* __restrict__ W_fc1, const T* __restrict__ W_fc2,
    const int* __restrict__ edge_src, const int* __restrict__ edge_dst,
    const int* __restrict__ sorted_idx, const int* __restrict__ wstart,
    const __hip_bfloat16* __restrict__ l_table,
    __hip_bfloat16* __restrict__ s_table,
    __hip_bfloat16* sW1T, short* sW2B, short* sHW,
    int* sSrc, int* sDst, float* sAttr, int* sWs)
{
    __hip_bfloat16* sHWb = reinterpret_cast<__hip_bfloat16*>(sHW);
    const int tid = threadIdx.x;
    const int lane = tid & 63;
    const int wid = tid >> 6;
    const int quad = lane >> 4;
    const int m16 = lane & 15;
    const int wb16 = wid * 16;
    const int whw = wid * WAVE_HW;

    if (tid < 5) sWs[tid] = wstart[blockIdx.x * 4 + tid];
    for (int i = tid; i < NBASIS * NRADIAL; i += 256) {
        int k = i / NBASIS, b = i - k * NBASIS;
        sW1T[k * 16 + b] = __float2bfloat16(ldv(W_fc1, (size_t)b * NRADIAL + k));
    }
    for (int i = tid; i < 12 * 4 * 64 * 8; i += 256) {
        int j = i & 7, ln = (i >> 3) & 63, kt = (i >> 9) & 3, t = i >> 11;
        int k = kt * 32 + ((ln >> 4) * 8) + j;
        int n = t * 16 + (ln & 15);
        reinterpret_cast<__hip_bfloat16*>(sW2B)[i] =
            (k < NRADIAL) ? __float2bfloat16(ldv(W_fc2, (size_t)k * WNUMEL + n))
                          : __float2bfloat16(0.f);
    }
    __syncthreads();

    const int e0r = tid >> 2;       // row 0..63 (16 per wave)
    const int part = tid & 3;       // k-quarter of the row's MLP
    const int rwave = e0r >> 4;     // wave owning this row
    const int r16 = e0r & 15;
    const int hbase = rwave * WAVE_HW + r16 * HSTRIDE;

    const int ws_r = sWs[rwave];            // row's wave chunk bounds
    const int we_r = sWs[rwave + 1];
    const int ws_w = sWs[wid];              // own wave chunk bounds (phase 3)
    const int we_w = sWs[wid + 1];

    int nwinB = 0;                           // block-uniform window count
#pragma unroll
    for (int i = 0; i < 4; ++i) {
        int nw = (sWs[i + 1] - sWs[i] + 15) >> 4;
        nwinB = max(nwinB, nw);
    }

    // ---- prologue: prefetch window 0 (always fully valid; chunk >= 350)
    int eg = sorted_idx[ws_r + r16];
    float elv[NBASIS];
#pragma unroll
    for (int b = 0; b < NBASIS; ++b) elv[b] = ldv(el, (size_t)eg * NBASIS + b);
    int mi = 0; float ma = 0.f, mb = 0.f;
    if (part == 0)      mi = edge_src[eg];
    else if (part == 1) mi = edge_dst[eg];
    else if (part == 2) { ma = ldv(edge_attr, (size_t)eg * 4 + 0); mb = ldv(edge_attr, (size_t)eg * 4 + 1); }
    else                { ma = ldv(edge_attr, (size_t)eg * 4 + 2); mb = ldv(edge_attr, (size_t)eg * 4 + 3); }

    float A0 = 0.f, A1x = 0.f, A1y = 0.f, A1z = 0.f;
    float A2x = 0.f, A2y = 0.f, A2z = 0.f, A3 = 0.f;
    int cur_dst = -1;

    for (int it = 0; it < nwinB; ++it) {
        // ---- metadata stage (registers -> LDS); clamped duplicates are
        // written for invalid rows but never read (phase 3 breaks first)
        if (part == 0)      sSrc[e0r] = mi;
        else if (part == 1) sDst[e0r] = mi;
        else if (part == 2) { sAttr[e0r * 4 + 0] = ma; sAttr[e0r * 4 + 1] = mb; }
        else                { sAttr[e0r * 4 + 2] = ma; sAttr[e0r * 4 + 3] = mb; }

        // ---- phase 0: layer-1 MLP from register elv
        {
            const float HS = 0.04472135954999579f;
            for (int kk = 0; kk < 25; ++kk) {
                int k = part * 25 + kk;
                const unsigned int* wp = (const unsigned int*)&sW1T[k * 16];
                float z = 0.f;
#pragma unroll
                for (int b2 = 0; b2 < 5; ++b2) {
                    unsigned int w2 = wp[b2];
                    __hip_bfloat162 hw;
                    __builtin_memcpy(&hw, &w2, 4);
                    z += elv[2 * b2] * b2f(hw.x) + elv[2 * b2 + 1] * b2f(hw.y);
                }
                sHWb[hbase + k] = __float2bfloat16(fmaxf(z, 0.f) * HS);
            }
            for (int k = 100 + part * 7; k < 107 + part * 7; ++k)
                sHWb[hbase + k] = __float2bfloat16(0.f);
        }

        // ---- issue next window's sorted_idx load (clamped to chunk end)
        int np = ws_r + (it + 1) * 16 + r16;
        int npc = (np < we_r) ? np : (we_r - 1);
        int next_eg = sorted_idx[npc];

        sync_lds();

        // ---- phase 1: A-fragment loads (wave's 16 edges)
        short8 afrag[4];
#pragma unroll
        for (int kt = 0; kt < 4; ++kt)
            afrag[kt] = *(const short8*)&sHW[whw + m16 * HSTRIDE + kt * 32 + quad * 8];

        // ---- phase-3 gather prefetch: 16-deep l_table reads fly during GEMM
        int srcs[16];
#pragma unroll
        for (int i = 0; i < 16; ++i) srcs[i] = sSrc[wb16 + i];
        float y0p[16];
        float y1p[16][3];
#pragma unroll
        for (int i = 0; i < 16; ++i)
            y0p[i] = b2f(l_table[(size_t)srcs[i] * 160 + lane]);
        if (lane < 32) {
#pragma unroll
            for (int i = 0; i < 16; ++i) {
                const __hip_bfloat16* lrow = l_table + (size_t)srcs[i] * 160 + 64 + lane * 3;
                y1p[i][0] = b2f(lrow[0]);
                y1p[i][1] = b2f(lrow[1]);
                y1p[i][2] = b2f(lrow[2]);
            }
        }

        // ---- phase 2: GEMM w = h @ W2 into this wave's sHW rows
#pragma unroll
        for (int t = 0; t < 12; ++t) {
            f32x4 acc = {0.f, 0.f, 0.f, 0.f};
#pragma unroll
            for (int kt = 0; kt < 4; ++kt) {
                short8 bfrag = *(const short8*)&sW2B[(((t * 4) + kt) * 64 + lane) * 8];
                acc = __builtin_amdgcn_mfma_f32_16x16x32_bf16(afrag[kt], bfrag, acc, 0, 0, 0);
            }
#pragma unroll
            for (int r = 0; r < 4; ++r)
                sHWb[whw + (quad * 4 + r) * WSTRIDE + t * 16 + m16] = __float2bfloat16(acc[r]);
        }

        // ---- issue next window's elv / metadata loads (hidden under phase 3)
        float elvN[NBASIS]; int miN = 0; float maN = 0.f, mbN = 0.f;
#pragma unroll
        for (int b = 0; b < NBASIS; ++b) elvN[b] = ldv(el, (size_t)next_eg * NBASIS + b);
        if (part == 0)      miN = edge_src[next_eg];
        else if (part == 1) miN = edge_dst[next_eg];
        else if (part == 2) { maN = ldv(edge_attr, (size_t)next_eg * 4 + 0); mbN = ldv(edge_attr, (size_t)next_eg * 4 + 1); }
        else                { maN = ldv(edge_attr, (size_t)next_eg * 4 + 2); mbN = ldv(edge_attr, (size_t)next_eg * 4 + 3); }

        sync_lds();

        // ---- phase 3: run-aggregated messages; wave-uniform validity break
        int nval = we_w - (ws_w + it * 16);   // edges valid in this window
#pragma unroll
        for (int i = 0; i < 16; ++i) {
            if (i >= nval) break;
            int elc = wb16 + i;
            int dst = sDst[elc];
            if (dst != cur_dst) {
                store_acc(s_table, cur_dst, lane, A0, A1x, A1y, A1z, A2x, A2y, A2z, A3);
                A0 = A1x = A1y = A1z = A2x = A2y = A2z = A3 = 0.f;
                cur_dst = dst;
            }
            float e0  = sAttr[elc * 4 + 0];
            float e1x = sAttr[elc * 4 + 1];
            float e1y = sAttr[elc * 4 + 2];
            float e1z = sAttr[elc * 4 + 3];

            int wrow = whw + i * WSTRIDE;
            float y0 = y0p[i];
            float w_a = b2f(sHWb[wrow + lane]);
            float w_b = b2f(sHWb[wrow + 64 + lane]);

            A0 += w_a * y0 * e0;
            float m1b = w_b * y0;
            A1x += m1b * e1x; A1y += m1b * e1y; A1z += m1b * e1z;
            if (lane < 32) {
                float w_c = b2f(sHWb[wrow + 128 + lane]);
                float w3v = b2f(sHWb[wrow + 160 + lane]);
                float g = w_c * e0;
                A2x += g * y1p[i][0]; A2y += g * y1p[i][1]; A2z += g * y1p[i][2];
                float dot = y1p[i][0] * e1x + y1p[i][1] * e1y + y1p[i][2] * e1z;
                A3 += w3v * dot * 0.5773502691896258f;
            }
        }

        eg = next_eg;
#pragma unroll
        for (int b = 0; b < NBASIS; ++b) elv[b] = elvN[b];
        mi = miN; ma = maN; mb = mbN;

        sync_lds();
    }
    // final store of the carried run (each node exclusively owned: plain store)
    store_acc(s_table, cur_dst, lane, A0, A1x, A1y, A1z, A2x, A2y, A2z, A3);
}

__global__ __launch_bounds__(256, 2) void edge_kernel(
    const void* edge_attr, const void* el, const void* W_fc1, const void* W_fc2,
    const int* edge_src, const int* edge_dst, const int* sorted_idx,
    const int* wstart, const void* l_table, __hip_bfloat16* s_table,
    const void* node_attr)
{
    __shared__ __hip_bfloat16 sW1T[NRADIAL * 16];
    __shared__ short sW2B[12 * 4 * 64 * 8];
    __shared__ short sHW[64 * WSTRIDE];
    __shared__ int sSrc[64], sDst[64];
    __shared__ float sAttr[256];
    __shared__ int sWs[5];
    if (input_is_f32(node_attr))
        edge_body<float>((const float*)edge_attr, (const float*)el,
                         (const float*)W_fc1, (const float*)W_fc2,
                         edge_src, edge_dst, sorted_idx, wstart,
                         (const __hip_bfloat16*)l_table, s_table,
                         sW1T, sW2B, sHW, sSrc, sDst, sAttr, sWs);
    else
        edge_body<__hip_bfloat16>((const __hip_bfloat16*)edge_attr,
                                  (const __hip_bfloat16*)el,
                                  (const __hip_bfloat16*)W_fc1,
                                  (const __hip_bfloat16*)W_fc2,
                                  edge_src, edge_dst, sorted_idx, wstart,
                                  (const __hip_bfloat16*)l_table, s_table,
                                  sW1T, sW2B, sHW, sSrc, sDst, sAttr, sWs);
}

// ---------------------------------------------------------------------------
// Kernel 3: output via MFMA (layout HW-validated); templated input type.
// ---------------------------------------------------------------------------
template <class TI, class TA, class TO>
__device__ __forceinline__ void output_mfma_t(
    const TI* __restrict__ ni, const TA* __restrict__ na,
    const TI* __restrict__ Wsi0, const TI* __restrict__ Wsi1,
    const TI* __restrict__ W00, const TI* __restrict__ W10,
    const TI* __restrict__ W01, const TI* __restrict__ W11,
    const short* __restrict__ st, TO* __restrict__ out,
    short* sBa, short* sBb)
{
    const int tid = threadIdx.x;
    const int lane = tid & 63;
    const int wid = tid >> 6;
    const int quad = lane >> 4;
    const int m16 = lane & 15;
    const float OC = 0.5f * 0.25f / 9.797958971132712f;
    const float SI1C = 0.17677669529663687f;

    // Ba: 20 frags f = ct*5+kt (ct 0..3, kt 0..4); K rows: [Wsi0 64 | W00 64 | W10 32]
    for (int i = tid; i < 20 * 512; i += 256) {
        int j = i & 7, ln = (i >> 3) & 63, f = i >> 9;
        int kt = f % 5, ct = f / 5;
        int k = kt * 32 + ((ln >> 4) << 3) + j;
        int col = ct * 16 + (ln & 15);
        short v;
        if (k < 64)       v = ldbf(Wsi0, (size_t)k * 64 + col);
        else if (k < 128) v = ldbf(W00, (size_t)(k - 64) * 64 + col);
        else              v = ldbf(W10, (size_t)(k - 128) * 64 + col);
        sBa[i] = v;
    }
    // Bb: 8 frags f = ct*4+kt (ct 0..1, kt 0..3); K rows: [Wsi1 32 | W01 64 | W11 32]
    for (int i = tid; i < 8 * 512; i += 256) {
        int j = i & 7, ln = (i >> 3) & 63, f = i >> 9;
        int kt = f & 3, ct = f >> 2;
        int k = kt * 32 + ((ln >> 4) << 3) + j;
        int col = ct * 16 + (ln & 15);
        short v;
        if (k < 32)      v = ldbf(Wsi1, (size_t)k * 32 + col);
        else if (k < 96) v = ldbf(W01, (size_t)(k - 32) * 32 + col);
        else             v = ldbf(W11, (size_t)(k - 96) * 32 + col);
        sBb[i] = v;
    }
    __syncthreads();

    int gw = blockIdx.x * 4 + wid;
    int nwv = gridDim.x * 4;
    for (int tile = gw; tile < OTILES; tile += nwv) {
        int tb = tile * 16;
        const TI* nrow = ni + (size_t)(tb + m16) * 160;
        const short* srow = st + (size_t)(tb + m16) * 384;

        short8 af[5];
        af[0] = frag8(nrow + quad * 8);
        af[1] = frag8(nrow + 32 + quad * 8);
        af[2] = *(const short8*)(srow + quad * 8);
        af[3] = *(const short8*)(srow + 32 + quad * 8);
        af[4] = *(const short8*)(srow + 352 + quad * 8);

        float an[4];
#pragma unroll
        for (int r = 0; r < 4; ++r) an[r] = ldv(na, tb + quad * 4 + r);

#pragma unroll
        for (int ct = 0; ct < 4; ++ct) {
            f32x4 aS = {0.f, 0.f, 0.f, 0.f};
            f32x4 aO = {0.f, 0.f, 0.f, 0.f};
            aS = __builtin_amdgcn_mfma_f32_16x16x32_bf16(
                af[0], *(const short8*)&sBa[(ct * 5 + 0) * 512 + lane * 8], aS, 0, 0, 0);
            aS = __builtin_amdgcn_mfma_f32_16x16x32_bf16(
                af[1], *(const short8*)&sBa[(ct * 5 + 1) * 512 + lane * 8], aS, 0, 0, 0);
            aO = __builtin_amdgcn_mfma_f32_16x16x32_bf16(
                af[2], *(const short8*)&sBa[(ct * 5 + 2) * 512 + lane * 8], aO, 0, 0, 0);
            aO = __builtin_amdgcn_mfma_f32_16x16x32_bf16(
                af[3], *(const short8*)&sBa[(ct * 5 + 3) * 512 + lane * 8], aO, 0, 0, 0);
            aO = __builtin_amdgcn_mfma_f32_16x16x32_bf16(
                af[4], *(const short8*)&sBa[(ct * 5 + 4) * 512 + lane * 8], aO, 0, 0, 0);
#pragma unroll
            for (int r = 0; r < 4; ++r)
                stout(out, (size_t)(tb + quad * 4 + r) * 160 + ct * 16 + m16,
                      an[r] * (0.125f * aS[r] + OC * aO[r]));
        }

        short8 bb[8];
#pragma unroll
        for (int q = 0; q < 8; ++q)
            bb[q] = *(const short8*)&sBb[q * 512 + lane * 8];

#pragma unroll
        for (int d = 0; d < 3; ++d) {
            short8 ax;
#pragma unroll
            for (int j = 0; j < 8; ++j)
                ax[j] = ldbf(nrow, 64 + (quad * 8 + j) * 3 + d);
            short8 as1a = *(const short8*)(srow + 64 + d * 64 + quad * 8);
            short8 as1b = *(const short8*)(srow + 64 + d * 64 + 32 + quad * 8);
            short8 as2  = *(const short8*)(srow + 256 + d * 32 + quad * 8);
#pragma unroll
            for (int ct = 0; ct < 2; ++ct) {
                f32x4 aS = {0.f, 0.f, 0.f, 0.f};
                f32x4 aO = {0.f, 0.f, 0.f, 0.f};
                aS = __builtin_amdgcn_mfma_f32_16x16x32_bf16(ax,   bb[ct * 4 + 0], aS, 0, 0, 0);
                aO = __builtin_amdgcn_mfma_f32_16x16x32_bf16(as1a, bb[ct * 4 + 1], aO, 0, 0, 0);
                aO = __builtin_amdgcn_mfma_f32_16x16x32_bf16(as1b, bb[ct * 4 + 2], aO, 0, 0, 0);
                aO = __builtin_amdgcn_mfma_f32_16x16x32_bf16(as2,  bb[ct * 4 + 3], aO, 0, 0, 0);
#pragma unroll
                for (int r = 0; r < 4; ++r)
                    stout(out, (size_t)(tb + quad * 4 + r) * 160 + 64 + (ct * 16 + m16) * 3 + d,
                          an[r] * (SI1C * aS[r] + OC * aO[r]));
            }
        }
    }
}

__global__ __launch_bounds__(256) void output_kernel(
    const void* node_input, const void* node_attr,
    const void* W_si0, const void* W_si1,
    const void* W_l2_00, const void* W_l2_10,
    const void* W_l2_01, const void* W_l2_11,
    const __hip_bfloat16* s_table, void* out)
{
    __shared__ __attribute__((aligned(16))) short sBa[20 * 512];  // 20 KB
    __shared__ __attribute__((aligned(16))) short sBb[8 * 512];   // 8 KB
    if (input_is_f32(node_attr))
        output_mfma_t<float, float, float>(
            (const float*)node_input, (const float*)node_attr,
            (const float*)W_si0, (const float*)W_si1,
            (const float*)W_l2_00, (const float*)W_l2_10,
            (const float*)W_l2_01, (const float*)W_l2_11,
            (const short*)s_table, (float*)out, sBa, sBb);
    else
        output_mfma_t<short, __hip_bfloat16, __hip_bfloat16>(
            (const short*)node_input, (const __hip_bfloat16*)node_attr,
            (const short*)W_si0, (const short*)W_si1,
            (const short*)W_l2_00, (const short*)W_l2_10,
            (const short*)W_l2_01, (const short*)W_l2_11,
            (const short*)s_table, (__hip_bfloat16*)out, sBa, sBb);
}

extern "C" void kernel_launch(void* const* d_in, const int* in_sizes, int n_in,
                              void* d_out, int out_size, void* d_ws, size_t ws_size,
                              hipStream_t stream)
{
    const void* node_input = d_in[0];
    const void* node_attr  = d_in[1];
    const void* edge_attr  = d_in[2];
    const void* el         = d_in[3];
    const void* W_si0  = d_in[4];
    const void* W_si1  = d_in[5];
    const void* W_l1_0 = d_in[6];
    const void* W_l1_1 = d_in[7];
    const void* W_l2_00 = d_in[8];
    const void* W_l2_10 = d_in[9];
    const void* W_l2_01 = d_in[10];
    const void* W_l2_11 = d_in[11];
    const void* W_fc1  = d_in[12];
    const void* W_fc2  = d_in[13];
    const int* edge_src = (const int*)d_in[14];
    const int* edge_dst = (const int*)d_in[15];

    // ws layout: s_table bf16 (38.4 MB) | sorted_idx (3.2 MB) | counts (0.2 MB)
    //            | wstart (2001 ints)
    __hip_bfloat16* s_table = (__hip_bfloat16*)d_ws;
    int* sorted_idx = (int*)((char*)d_ws + (size_t)N_NODES * 384 * 2);
    int* counts     = (int*)((char*)sorted_idx + (size_t)N_EDGES * 4);
    int* wstart     = counts + N_NODES;
    void* l_table = d_out;   // bf16, N*160 elements; overwritten by output_kernel

    size_t ws_used = (size_t)N_NODES * 384 * 2 + (size_t)N_EDGES * 4
                   + (size_t)N_NODES * 4 + (size_t)(NWAVES + 1) * 4;
    hipMemsetAsync(d_ws, 0, ws_used, stream);

    hist_kernel<<<(N_EDGES + 255) / 256, 256, 0, stream>>>(edge_dst, counts);
    scan_kernel<<<1, 1024, 0, stream>>>(counts);
    scatter_kernel<<<(N_EDGES + 255) / 256, 256, 0, stream>>>(edge_dst, counts, sorted_idx);
    segsort_kernel<<<(N_NODES + 255) / 256, 256, 0, stream>>>(counts, sorted_idx);
    snap_kernel<<<(NWAVES + 256) / 256, 256, 0, stream>>>(sorted_idx, edge_dst, wstart);

    node_linear_kernel<<<NODE_GRID, 256, 0, stream>>>(
        node_input, node_attr, W_l1_0, W_l1_1, l_table);
    edge_kernel<<<EDGE_GRID, 256, 0, stream>>>(
        edge_attr, el, W_fc1, W_fc2, edge_src, edge_dst, sorted_idx, wstart,
        l_table, s_table, node_attr);
    output_kernel<<<NODE_GRID, 256, 0, stream>>>(
        node_input, node_attr, W_si0, W_si1, W_l2_00, W_l2_10, W_l2_01, W_l2_11,
        s_table, d_out);
}